// Round 4
// baseline (2083.531 us; speedup 1.0000x reference)
//
#include <hip/hip_runtime.h>
#include <hip/hip_bf16.h>
#include <cstdint>
#include <cstddef>

typedef __attribute__((ext_vector_type(8))) __bf16 bf16x8;
typedef __attribute__((ext_vector_type(4))) float f32x4;
typedef __attribute__((ext_vector_type(4))) unsigned short us4;

#define GLOAD_LDS16(g, l)                                                        \
    __builtin_amdgcn_global_load_lds(                                            \
        (const __attribute__((address_space(1))) void*)(g),                      \
        (__attribute__((address_space(3))) void*)(l), 16, 0, 0)

static __device__ __forceinline__ unsigned short f2bf(float x) {
    unsigned int u = __builtin_bit_cast(unsigned int, x);
    return (unsigned short)((u + 0x7FFFu + ((u >> 16) & 1u)) >> 16);
}

// gelu(x) = x * sigmoid(1.5957691x + 0.0713548x^3)  (== tanh-form gelu)
static __device__ __forceinline__ float gelu_fast(float x) {
    const float p = x * x;
    const float u = x * fmaf(0.0713548162726f, p, 1.59576912161f);
    const float t = __expf(-u);
    return x * __builtin_amdgcn_rcpf(1.0f + t);
}

// ---------------- Router: logits -> softmax -> mask, plus h -> bf16 ----------
__global__ __launch_bounds__(256) void moe_router_kernel(
    const float* __restrict__ h, const float* __restrict__ Wr,
    const float* __restrict__ br, unsigned short* __restrict__ hbf,
    float* __restrict__ mw)
{
    const int lane = threadIdx.x & 63, wave = threadIdx.x >> 6;
    const int n = blockIdx.x * 4 + wave;  // one token per wave
    const float* hr = h + (size_t)n * 1024;
    const int base = lane * 16;

    float xs[16];
#pragma unroll
    for (int q = 0; q < 4; ++q) {
        f32x4 v = *(const f32x4*)(hr + base + q * 4);
        xs[q * 4 + 0] = v[0]; xs[q * 4 + 1] = v[1];
        xs[q * 4 + 2] = v[2]; xs[q * 4 + 3] = v[3];
    }
    float acc[8] = {0.f, 0.f, 0.f, 0.f, 0.f, 0.f, 0.f, 0.f};
#pragma unroll
    for (int j = 0; j < 16; ++j) {
        const float x = xs[j];
        const f32x4 w0 = *(const f32x4*)(Wr + (size_t)(base + j) * 8);
        const f32x4 w1 = *(const f32x4*)(Wr + (size_t)(base + j) * 8 + 4);
        acc[0] += x * w0[0]; acc[1] += x * w0[1]; acc[2] += x * w0[2]; acc[3] += x * w0[3];
        acc[4] += x * w1[0]; acc[5] += x * w1[1]; acc[6] += x * w1[2]; acc[7] += x * w1[3];
    }
#pragma unroll
    for (int q = 0; q < 4; ++q) {
        us4 o;
        o[0] = f2bf(xs[q * 4 + 0]); o[1] = f2bf(xs[q * 4 + 1]);
        o[2] = f2bf(xs[q * 4 + 2]); o[3] = f2bf(xs[q * 4 + 3]);
        *(us4*)(hbf + (size_t)n * 1024 + base + q * 4) = o;
    }
#pragma unroll
    for (int m = 32; m >= 1; m >>= 1)
#pragma unroll
        for (int e = 0; e < 8; ++e) acc[e] += __shfl_xor(acc[e], m, 64);

    if (lane == 0) {
        float l[8]; float mx = -1e30f;
#pragma unroll
        for (int e = 0; e < 8; ++e) { l[e] = acc[e] + br[e]; mx = fmaxf(mx, l[e]); }
        float s = 0.f;
#pragma unroll
        for (int e = 0; e < 8; ++e) { l[e] = __expf(l[e] - mx); s += l[e]; }
        const float inv = 1.0f / s;
#pragma unroll
        for (int e = 0; e < 8; ++e) {
            const float w = l[e] * inv;
            mw[(size_t)n * 8 + e] = (w > 0.05f) ? w : 0.0f;
        }
    }
}

// ---------- Transpose + fp32->bf16 convert (32x32 tiles, per expert z) -------
__global__ __launch_bounds__(256) void moe_tcvt_kernel(
    const float* __restrict__ in, unsigned short* __restrict__ out,
    int ls, size_t in_es, int os, size_t out_es)
{
    __shared__ unsigned short t[32][33];
    const int e = blockIdx.z;
    const int r = threadIdx.x >> 3, c = (threadIdx.x & 7) * 4;
    const float* I = in + (size_t)e * in_es + (size_t)(blockIdx.x * 32 + r) * ls + blockIdx.y * 32 + c;
    f32x4 v = *(const f32x4*)I;
    t[r][c + 0] = f2bf(v[0]); t[r][c + 1] = f2bf(v[1]);
    t[r][c + 2] = f2bf(v[2]); t[r][c + 3] = f2bf(v[3]);
    __syncthreads();
    unsigned short* O = out + (size_t)e * out_es + (size_t)(blockIdx.y * 32 + r) * os + blockIdx.x * 32 + c;
    us4 o;
    o[0] = t[c + 0][r]; o[1] = t[c + 1][r]; o[2] = t[c + 2][r]; o[3] = t[c + 3][r];
    *(us4*)O = o;
}

// ---------------- GEMM1: ghid = mw * gelu(h @ W1 + b1)  (bf16 out) -----------
// Swapped-operand MFMA: acc[i][j] holds D'[n][m] (reg walks n = F-col).
__global__ __launch_bounds__(256) void moe_gemm1_kernel(
    const unsigned short* __restrict__ A,   // hbf [N][1024]
    const unsigned short* __restrict__ B,   // W1t base (B^T layout, ldb=1024)
    size_t estrideB,
    const float* __restrict__ b1,           // [E][4096]
    const float* __restrict__ mw,           // [N][8]
    unsigned short* __restrict__ Cg,        // ghid [N][E*Fc]
    int Fc, int f0glob)
{
    __shared__ unsigned short Al[128 * 32];
    __shared__ unsigned short Bl[128 * 32];
    __shared__ float s_mw[128];
    const int tid = threadIdx.x, lane = tid & 63, wave = tid >> 6;

    // bijective XCD-chunk swizzle (total % 8 == 0)
    const int gx = gridDim.x, total = gx * gridDim.y;
    const int orig = blockIdx.x + blockIdx.y * gx;
    const int nid = (orig & 7) * (total >> 3) + (orig >> 3);
    const int bx = nid % gx, by = nid / gx;

    const int m0 = bx * 128;
    const int colblk = by * 128;
    const int e = colblk / Fc;              // Fc >= 128 -> tile within one expert
    const int fbase = colblk - e * Fc;
    const unsigned short* Bp = B + (size_t)e * estrideB + (size_t)fbase * 1024;
    if (tid < 128) s_mw[tid] = mw[(size_t)(m0 + tid) * 8 + e];

    f32x4 acc[4][4] = {};
    const int wr = wave >> 1, wc = wave & 1;
    const int aoff = (wr * 64 + (lane & 15)) * 32 + (lane >> 4) * 8;
    const int boff = (wc * 64 + (lane & 15)) * 32 + (lane >> 4) * 8;
    const int r0 = tid >> 2, c80 = (tid & 3) * 8;
    const int r1 = (256 + tid) >> 2, c81 = ((256 + tid) & 3) * 8;
    char* la0 = (char*)Al + (size_t)((wave << 6) * 16);
    char* la1 = (char*)Al + (size_t)((256 + (wave << 6)) * 16);
    char* lb0 = (char*)Bl + (size_t)((wave << 6) * 16);
    char* lb1 = (char*)Bl + (size_t)((256 + (wave << 6)) * 16);

    for (int k0 = 0; k0 < 1024; k0 += 32) {
        GLOAD_LDS16(A + (size_t)(m0 + r0) * 1024 + k0 + c80, la0);
        GLOAD_LDS16(A + (size_t)(m0 + r1) * 1024 + k0 + c81, la1);
        GLOAD_LDS16(Bp + (size_t)r0 * 1024 + k0 + c80, lb0);
        GLOAD_LDS16(Bp + (size_t)r1 * 1024 + k0 + c81, lb1);
        __syncthreads();
        bf16x8 af[4], bq[4];
#pragma unroll
        for (int i = 0; i < 4; ++i) {
            af[i] = *(const bf16x8*)&Al[aoff + i * 512];
            bq[i] = *(const bf16x8*)&Bl[boff + i * 512];
        }
#pragma unroll
        for (int i = 0; i < 4; ++i)
#pragma unroll
            for (int j = 0; j < 4; ++j)
                acc[i][j] = __builtin_amdgcn_mfma_f32_16x16x32_bf16(bq[j], af[i], acc[i][j], 0, 0, 0);
        __syncthreads();
    }

    // Epilogue: lane holds 4 consecutive F-cols (reg) for token = lane&15.
    const int tcol = lane & 15;
    const int nr0 = (lane >> 4) * 4;
    const size_t ldC = (size_t)Fc * 8;
    const float* b1p = b1 + (size_t)e * 4096 + f0glob + fbase;
    f32x4 b1v[4];
#pragma unroll
    for (int j = 0; j < 4; ++j)
        b1v[j] = *(const f32x4*)(b1p + wc * 64 + j * 16 + nr0);
#pragma unroll
    for (int i = 0; i < 4; ++i) {
        const int token = wr * 64 + i * 16 + tcol;
        const float w = s_mw[token];
        unsigned short* crow = Cg + (size_t)(m0 + token) * ldC + colblk;
#pragma unroll
        for (int j = 0; j < 4; ++j) {
            const int n = wc * 64 + j * 16 + nr0;
            us4 o;
#pragma unroll
            for (int r = 0; r < 4; ++r)
                o[r] = f2bf(w * gelu_fast(acc[i][j][r] + b1v[j][r]));
            *(us4*)(crow + n) = o;
        }
    }
}

// ------- GEMM2: part[z] (+)= ghid[:, klo:khi] @ W2  (split-K, fp32) ----------
__global__ __launch_bounds__(256) void moe_gemm2_kernel(
    const unsigned short* __restrict__ A,   // ghid [N][ldA]
    const unsigned short* __restrict__ B,   // W2t base (B^T layout)
    size_t estrideB, int ldb,
    float* __restrict__ part,               // S x [N][1024] fp32 partials
    int ldA, int kspan, int logFc, int init)
{
    __shared__ unsigned short Al[128 * 32];
    __shared__ unsigned short Bl[128 * 32];
    const int tid = threadIdx.x, lane = tid & 63, wave = tid >> 6;

    const int gx = gridDim.x, total = gx * gridDim.y;
    const int orig = blockIdx.x + blockIdx.y * gx;
    const int nid = (orig & 7) * (total >> 3) + (orig >> 3);
    const int bx = nid % gx, by = nid / gx;
    const int m0 = bx * 128, n0 = by * 128;

    const int z = blockIdx.z;
    float* Cacc = part + (size_t)z * (8192 * 1024);
    const int klo = z * kspan, khi = klo + kspan;

    f32x4 acc[4][4] = {};
    const int wr = wave >> 1, wc = wave & 1;
    const int aoff = (wr * 64 + (lane & 15)) * 32 + (lane >> 4) * 8;
    const int boff = (wc * 64 + (lane & 15)) * 32 + (lane >> 4) * 8;
    const int r0 = tid >> 2, c80 = (tid & 3) * 8;
    const int r1 = (256 + tid) >> 2, c81 = ((256 + tid) & 3) * 8;
    char* la0 = (char*)Al + (size_t)((wave << 6) * 16);
    char* la1 = (char*)Al + (size_t)((256 + (wave << 6)) * 16);
    char* lb0 = (char*)Bl + (size_t)((wave << 6) * 16);
    char* lb1 = (char*)Bl + (size_t)((256 + (wave << 6)) * 16);

    for (int k0 = klo; k0 < khi; k0 += 32) {
        const int e = k0 >> logFc;
        const int kc0 = k0 - (e << logFc);
        const unsigned short* Bp = B + (size_t)e * estrideB + kc0;
        GLOAD_LDS16(A + (size_t)(m0 + r0) * ldA + k0 + c80, la0);
        GLOAD_LDS16(A + (size_t)(m0 + r1) * ldA + k0 + c81, la1);
        GLOAD_LDS16(Bp + (size_t)(n0 + r0) * ldb + c80, lb0);
        GLOAD_LDS16(Bp + (size_t)(n0 + r1) * ldb + c81, lb1);
        __syncthreads();
        bf16x8 af[4], bq[4];
#pragma unroll
        for (int i = 0; i < 4; ++i) {
            af[i] = *(const bf16x8*)&Al[aoff + i * 512];
            bq[i] = *(const bf16x8*)&Bl[boff + i * 512];
        }
#pragma unroll
        for (int i = 0; i < 4; ++i)
#pragma unroll
            for (int j = 0; j < 4; ++j)
                acc[i][j] = __builtin_amdgcn_mfma_f32_16x16x32_bf16(bq[j], af[i], acc[i][j], 0, 0, 0);
        __syncthreads();
    }

    // Epilogue: vector f32x4 accumulate; lane holds 4 consecutive d-cols.
    const int tcol = lane & 15;
    const int nr0 = (lane >> 4) * 4;
#pragma unroll
    for (int i = 0; i < 4; ++i) {
        const int token = wr * 64 + i * 16 + tcol;
        float* cp = Cacc + (size_t)(m0 + token) * 1024 + n0;
#pragma unroll
        for (int j = 0; j < 4; ++j) {
            const int n = wc * 64 + j * 16 + nr0;
            f32x4 v = acc[i][j];
            if (init) {
                *(f32x4*)(cp + n) = v;
            } else {
                f32x4 old = *(const f32x4*)(cp + n);
                *(f32x4*)(cp + n) = old + v;
            }
        }
    }
}

// ------------- Combine: out = sum_z part[z] + sum_e mw*b2 --------------------
__global__ __launch_bounds__(256) void moe_combine_kernel(
    const float* __restrict__ part, int S,
    float* __restrict__ out, const float* __restrict__ mw,
    const float* __restrict__ b2)
{
    const int n = blockIdx.x, t = threadIdx.x;
    const int d = t * 4;
    f32x4 v = *(const f32x4*)(part + (size_t)n * 1024 + d);
    for (int z = 1; z < S; ++z)
        v = v + *(const f32x4*)(part + (size_t)z * (8192 * 1024) + (size_t)n * 1024 + d);
#pragma unroll
    for (int e = 0; e < 8; ++e) {
        const float w = mw[(size_t)n * 8 + e];
        const f32x4 b = *(const f32x4*)(b2 + (size_t)e * 1024 + d);
        v = v + w * b;
    }
    *(f32x4*)(out + (size_t)n * 1024 + d) = v;
}

extern "C" void kernel_launch(void* const* d_in, const int* in_sizes, int n_in,
                              void* d_out, int out_size, void* d_ws, size_t ws_size,
                              hipStream_t stream)
{
    (void)in_sizes; (void)n_in; (void)out_size;
    const float* h  = (const float*)d_in[0];
    const float* Wr = (const float*)d_in[1];
    const float* br = (const float*)d_in[2];
    const float* W1 = (const float*)d_in[3];
    const float* b1 = (const float*)d_in[4];
    const float* W2 = (const float*)d_in[5];
    const float* b2 = (const float*)d_in[6];
    float* out = (float*)d_out;   // fp32 output [N][D]

    const int N = 8192, D = 1024, F = 4096, E = 8;
    auto al = [](size_t x) { return (x + 255) & ~(size_t)255; };
    const size_t sz_hbf = al((size_t)N * D * 2);
    const size_t sz_mw  = al((size_t)N * E * 4);
    const size_t sz_pt1 = al((size_t)N * D * 4);           // one fp32 partial
    auto tot = [&](int fc, int S, bool full) {
        size_t s = sz_hbf + sz_mw + al((size_t)N * E * fc * 2);
        s += (full ? al((size_t)E * F * D * 2) : al((size_t)E * fc * D * 2)) * 2;
        if (S > 1) s += (size_t)S * sz_pt1;
        return s;
    };
    int Fc, S; bool full;
    if      (tot(2048, 4, true)  <= ws_size) { Fc = 2048; S = 4; full = true;  }
    else if (tot(1024, 2, true)  <= ws_size) { Fc = 1024; S = 2; full = true;  }
    else if (tot(512,  2, true)  <= ws_size) { Fc = 512;  S = 2; full = true;  }
    else if (tot(1024, 1, true)  <= ws_size) { Fc = 1024; S = 1; full = true;  }
    else if (tot(512,  1, true)  <= ws_size) { Fc = 512;  S = 1; full = true;  }
    else if (tot(512,  1, false) <= ws_size) { Fc = 512;  S = 1; full = false; }
    else if (tot(256,  1, false) <= ws_size) { Fc = 256;  S = 1; full = false; }
    else                                     { Fc = 128;  S = 1; full = false; }
    const int logFc = (Fc == 2048) ? 11 : (Fc == 1024) ? 10 : (Fc == 512) ? 9
                    : (Fc == 256) ? 8 : 7;

    char* p = (char*)d_ws;
    unsigned short* hbf = (unsigned short*)p; p += sz_hbf;
    float* mwp  = (float*)p; p += sz_mw;
    unsigned short* ghid = (unsigned short*)p; p += al((size_t)N * E * Fc * 2);
    unsigned short* W1t  = (unsigned short*)p;
    p += full ? al((size_t)E * F * D * 2) : al((size_t)E * Fc * D * 2);
    unsigned short* W2t  = (unsigned short*)p;
    p += full ? al((size_t)E * F * D * 2) : al((size_t)E * Fc * D * 2);
    float* part = (S > 1) ? (float*)p : out;   // S==1: accumulate into out

    moe_router_kernel<<<N / 4, 256, 0, stream>>>(h, Wr, br, hbf, mwp);

    if (full) {
        moe_tcvt_kernel<<<dim3(D / 32, F / 32, E), 256, 0, stream>>>(
            W1, W1t, F, (size_t)D * F, D, (size_t)F * D);
        moe_tcvt_kernel<<<dim3(F / 32, D / 32, E), 256, 0, stream>>>(
            W2, W2t, D, (size_t)F * D, F, (size_t)D * F);
    }

    const int nch = F / Fc;
    const int Kc = E * Fc;
    for (int c = 0; c < nch; ++c) {
        if (!full) {
            moe_tcvt_kernel<<<dim3(D / 32, Fc / 32, E), 256, 0, stream>>>(
                W1 + (size_t)c * Fc, W1t, F, (size_t)D * F, D, (size_t)Fc * D);
            moe_tcvt_kernel<<<dim3(Fc / 32, D / 32, E), 256, 0, stream>>>(
                W2 + (size_t)c * Fc * D, W2t, D, (size_t)F * D, Fc, (size_t)D * Fc);
        }
        const unsigned short* B1p = W1t + (full ? (size_t)c * Fc * D : 0);
        const size_t es1 = full ? (size_t)F * D : (size_t)Fc * D;
        moe_gemm1_kernel<<<dim3(N / 128, Kc / 128), 256, 0, stream>>>(
            hbf, B1p, es1, b1, mwp, ghid, Fc, c * Fc);

        const unsigned short* B2p = W2t + (full ? (size_t)c * Fc : 0);
        const size_t es2 = full ? (size_t)D * F : (size_t)D * Fc;
        const int ldb2 = full ? F : Fc;
        moe_gemm2_kernel<<<dim3(N / 128, D / 128, S), 256, 0, stream>>>(
            ghid, B2p, es2, ldb2, part, Kc, Kc / S, logFc, (c == 0) ? 1 : 0);
    }

    moe_combine_kernel<<<N, 256, 0, stream>>>(part, S, out, mwp, b2);
}

// Round 5
// 1938.349 us; speedup vs baseline: 1.0749x; 1.0749x over previous
//
#include <hip/hip_runtime.h>
#include <hip/hip_bf16.h>
#include <cstdint>
#include <cstddef>

typedef __attribute__((ext_vector_type(8))) __bf16 bf16x8;
typedef __attribute__((ext_vector_type(4))) float f32x4;
typedef __attribute__((ext_vector_type(4))) unsigned short us4;

#define GLOAD_LDS16(g, l)                                                        \
    __builtin_amdgcn_global_load_lds(                                            \
        (const __attribute__((address_space(1))) void*)(g),                      \
        (__attribute__((address_space(3))) void*)(l), 16, 0, 0)

static __device__ __forceinline__ unsigned short f2bf(float x) {
    unsigned int u = __builtin_bit_cast(unsigned int, x);
    return (unsigned short)((u + 0x7FFFu + ((u >> 16) & 1u)) >> 16);
}

// gelu(x) = x * sigmoid(1.5957691x + 0.0713548x^3)  (== tanh-form gelu)
static __device__ __forceinline__ float gelu_fast(float x) {
    const float p = x * x;
    const float u = x * fmaf(0.0713548162726f, p, 1.59576912161f);
    const float t = __expf(-u);
    return x * __builtin_amdgcn_rcpf(1.0f + t);
}

// ---------------- Router: logits -> softmax -> mask, plus h -> bf16 ----------
__global__ __launch_bounds__(256) void moe_router_kernel(
    const float* __restrict__ h, const float* __restrict__ Wr,
    const float* __restrict__ br, unsigned short* __restrict__ hbf,
    float* __restrict__ mw)
{
    const int lane = threadIdx.x & 63, wave = threadIdx.x >> 6;
    const int n = blockIdx.x * 4 + wave;  // one token per wave
    const float* hr = h + (size_t)n * 1024;
    const int base = lane * 16;

    float xs[16];
#pragma unroll
    for (int q = 0; q < 4; ++q) {
        f32x4 v = *(const f32x4*)(hr + base + q * 4);
        xs[q * 4 + 0] = v[0]; xs[q * 4 + 1] = v[1];
        xs[q * 4 + 2] = v[2]; xs[q * 4 + 3] = v[3];
    }
    float acc[8] = {0.f, 0.f, 0.f, 0.f, 0.f, 0.f, 0.f, 0.f};
#pragma unroll
    for (int j = 0; j < 16; ++j) {
        const float x = xs[j];
        const f32x4 w0 = *(const f32x4*)(Wr + (size_t)(base + j) * 8);
        const f32x4 w1 = *(const f32x4*)(Wr + (size_t)(base + j) * 8 + 4);
        acc[0] += x * w0[0]; acc[1] += x * w0[1]; acc[2] += x * w0[2]; acc[3] += x * w0[3];
        acc[4] += x * w1[0]; acc[5] += x * w1[1]; acc[6] += x * w1[2]; acc[7] += x * w1[3];
    }
#pragma unroll
    for (int q = 0; q < 4; ++q) {
        us4 o;
        o[0] = f2bf(xs[q * 4 + 0]); o[1] = f2bf(xs[q * 4 + 1]);
        o[2] = f2bf(xs[q * 4 + 2]); o[3] = f2bf(xs[q * 4 + 3]);
        *(us4*)(hbf + (size_t)n * 1024 + base + q * 4) = o;
    }
#pragma unroll
    for (int m = 32; m >= 1; m >>= 1)
#pragma unroll
        for (int e = 0; e < 8; ++e) acc[e] += __shfl_xor(acc[e], m, 64);

    if (lane == 0) {
        float l[8]; float mx = -1e30f;
#pragma unroll
        for (int e = 0; e < 8; ++e) { l[e] = acc[e] + br[e]; mx = fmaxf(mx, l[e]); }
        float s = 0.f;
#pragma unroll
        for (int e = 0; e < 8; ++e) { l[e] = __expf(l[e] - mx); s += l[e]; }
        const float inv = 1.0f / s;
#pragma unroll
        for (int e = 0; e < 8; ++e) {
            const float w = l[e] * inv;
            mw[(size_t)n * 8 + e] = (w > 0.05f) ? w : 0.0f;
        }
    }
}

// ---------- Transpose + fp32->bf16 convert (32x32 tiles, per expert z) -------
__global__ __launch_bounds__(256) void moe_tcvt_kernel(
    const float* __restrict__ in, unsigned short* __restrict__ out,
    int ls, size_t in_es, int os, size_t out_es)
{
    __shared__ unsigned short t[32][33];
    const int e = blockIdx.z;
    const int r = threadIdx.x >> 3, c = (threadIdx.x & 7) * 4;
    const float* I = in + (size_t)e * in_es + (size_t)(blockIdx.x * 32 + r) * ls + blockIdx.y * 32 + c;
    f32x4 v = *(const f32x4*)I;
    t[r][c + 0] = f2bf(v[0]); t[r][c + 1] = f2bf(v[1]);
    t[r][c + 2] = f2bf(v[2]); t[r][c + 3] = f2bf(v[3]);
    __syncthreads();
    unsigned short* O = out + (size_t)e * out_es + (size_t)(blockIdx.y * 32 + r) * os + blockIdx.x * 32 + c;
    us4 o;
    o[0] = t[c + 0][r]; o[1] = t[c + 1][r]; o[2] = t[c + 2][r]; o[3] = t[c + 3][r];
    *(us4*)O = o;
}

// ---------------- GEMM1: ghid = mw * gelu(h @ W1 + b1)  (bf16 out) -----------
// Swapped-operand MFMA: acc[i][j] holds D'[n][m] (reg walks n = F-col).
__global__ __launch_bounds__(256) void moe_gemm1_kernel(
    const unsigned short* __restrict__ A,   // hbf [N][1024]
    const unsigned short* __restrict__ B,   // W1t base (B^T layout, ldb=1024)
    size_t estrideB,
    const float* __restrict__ b1,           // [E][4096]
    const float* __restrict__ mw,           // [N][8]
    unsigned short* __restrict__ Cg,        // ghid [N][E*Fc]
    int Fc, int f0glob)
{
    __shared__ unsigned short Al[128 * 32];
    __shared__ unsigned short Bl[128 * 32];
    __shared__ float s_mw[128];
    const int tid = threadIdx.x, lane = tid & 63, wave = tid >> 6;

    // bijective XCD-chunk swizzle (total % 8 == 0)
    const int gx = gridDim.x, total = gx * gridDim.y;
    const int orig = blockIdx.x + blockIdx.y * gx;
    const int nid = (orig & 7) * (total >> 3) + (orig >> 3);
    const int bx = nid % gx, by = nid / gx;

    const int m0 = bx * 128;
    const int colblk = by * 128;
    const int e = colblk / Fc;              // Fc >= 128 -> tile within one expert
    const int fbase = colblk - e * Fc;
    const unsigned short* Bp = B + (size_t)e * estrideB + (size_t)fbase * 1024;
    if (tid < 128) s_mw[tid] = mw[(size_t)(m0 + tid) * 8 + e];

    f32x4 acc[4][4] = {};
    const int wr = wave >> 1, wc = wave & 1;
    const int aoff = (wr * 64 + (lane & 15)) * 32 + (lane >> 4) * 8;
    const int boff = (wc * 64 + (lane & 15)) * 32 + (lane >> 4) * 8;
    const int r0 = tid >> 2, c80 = (tid & 3) * 8;
    const int r1 = (256 + tid) >> 2, c81 = ((256 + tid) & 3) * 8;
    char* la0 = (char*)Al + (size_t)((wave << 6) * 16);
    char* la1 = (char*)Al + (size_t)((256 + (wave << 6)) * 16);
    char* lb0 = (char*)Bl + (size_t)((wave << 6) * 16);
    char* lb1 = (char*)Bl + (size_t)((256 + (wave << 6)) * 16);

    for (int k0 = 0; k0 < 1024; k0 += 32) {
        GLOAD_LDS16(A + (size_t)(m0 + r0) * 1024 + k0 + c80, la0);
        GLOAD_LDS16(A + (size_t)(m0 + r1) * 1024 + k0 + c81, la1);
        GLOAD_LDS16(Bp + (size_t)r0 * 1024 + k0 + c80, lb0);
        GLOAD_LDS16(Bp + (size_t)r1 * 1024 + k0 + c81, lb1);
        __syncthreads();
        bf16x8 af[4], bq[4];
#pragma unroll
        for (int i = 0; i < 4; ++i) {
            af[i] = *(const bf16x8*)&Al[aoff + i * 512];
            bq[i] = *(const bf16x8*)&Bl[boff + i * 512];
        }
#pragma unroll
        for (int i = 0; i < 4; ++i)
#pragma unroll
            for (int j = 0; j < 4; ++j)
                acc[i][j] = __builtin_amdgcn_mfma_f32_16x16x32_bf16(bq[j], af[i], acc[i][j], 0, 0, 0);
        __syncthreads();
    }

    // Epilogue: lane holds 4 consecutive F-cols (reg) for token = lane&15.
    const int tcol = lane & 15;
    const int nr0 = (lane >> 4) * 4;
    const size_t ldC = (size_t)Fc * 8;
    const float* b1p = b1 + (size_t)e * 4096 + f0glob + fbase;
    f32x4 b1v[4];
#pragma unroll
    for (int j = 0; j < 4; ++j)
        b1v[j] = *(const f32x4*)(b1p + wc * 64 + j * 16 + nr0);
#pragma unroll
    for (int i = 0; i < 4; ++i) {
        const int token = wr * 64 + i * 16 + tcol;
        const float w = s_mw[token];
        unsigned short* crow = Cg + (size_t)(m0 + token) * ldC + colblk;
#pragma unroll
        for (int j = 0; j < 4; ++j) {
            const int n = wc * 64 + j * 16 + nr0;
            us4 o;
#pragma unroll
            for (int r = 0; r < 4; ++r)
                o[r] = f2bf(w * gelu_fast(acc[i][j][r] + b1v[j][r]));
            *(us4*)(crow + n) = o;
        }
    }
}

// ------- GEMM2: part[z] (+)= ghid[:, klo:khi] @ W2  (split-K, fp32) ----------
// XCD A-affinity mapping: XCD = blockIdx.x%8 (y,z drop out mod 8). Each XCD
// owns a disjoint 8-tile bx slice of A-rows and sweeps the 8 by-panels
// fastest, so its active A slice (128 rows x kspan) stays L2-resident and
// ghid is fetched once per dispatch; small W2t re-reads hit L3.
__global__ __launch_bounds__(256) void moe_gemm2_kernel(
    const unsigned short* __restrict__ A,   // ghid [N][ldA]
    const unsigned short* __restrict__ B,   // W2t base (B^T layout)
    size_t estrideB, int ldb,
    float* __restrict__ part,               // S x [N][1024] fp32 partials
    int ldA, int kspan, int logFc, int init)
{
    __shared__ unsigned short Al[128 * 32];
    __shared__ unsigned short Bl[128 * 32];
    const int tid = threadIdx.x, lane = tid & 63, wave = tid >> 6;

    // grid is (64, 8, S): orig in [0,512)
    const int orig = blockIdx.x + blockIdx.y * gridDim.x;
    const int c8 = orig & 7;        // XCD id
    const int j8 = orig >> 3;       // per-XCD sequence [0,64)
    const int by = j8 & 7;          // n-panel sweeps fastest
    const int bx = c8 * 8 + (j8 >> 3);
    const int m0 = bx * 128, n0 = by * 128;

    const int z = blockIdx.z;
    float* Cacc = part + (size_t)z * (8192 * 1024);
    const int klo = z * kspan, khi = klo + kspan;

    f32x4 acc[4][4] = {};
    const int wr = wave >> 1, wc = wave & 1;
    const int aoff = (wr * 64 + (lane & 15)) * 32 + (lane >> 4) * 8;
    const int boff = (wc * 64 + (lane & 15)) * 32 + (lane >> 4) * 8;
    const int r0 = tid >> 2, c80 = (tid & 3) * 8;
    const int r1 = (256 + tid) >> 2, c81 = ((256 + tid) & 3) * 8;
    char* la0 = (char*)Al + (size_t)((wave << 6) * 16);
    char* la1 = (char*)Al + (size_t)((256 + (wave << 6)) * 16);
    char* lb0 = (char*)Bl + (size_t)((wave << 6) * 16);
    char* lb1 = (char*)Bl + (size_t)((256 + (wave << 6)) * 16);

    for (int k0 = klo; k0 < khi; k0 += 32) {
        const int e = k0 >> logFc;
        const int kc0 = k0 - (e << logFc);
        const unsigned short* Bp = B + (size_t)e * estrideB + kc0;
        GLOAD_LDS16(A + (size_t)(m0 + r0) * ldA + k0 + c80, la0);
        GLOAD_LDS16(A + (size_t)(m0 + r1) * ldA + k0 + c81, la1);
        GLOAD_LDS16(Bp + (size_t)(n0 + r0) * ldb + c80, lb0);
        GLOAD_LDS16(Bp + (size_t)(n0 + r1) * ldb + c81, lb1);
        __syncthreads();
        bf16x8 af[4], bq[4];
#pragma unroll
        for (int i = 0; i < 4; ++i) {
            af[i] = *(const bf16x8*)&Al[aoff + i * 512];
            bq[i] = *(const bf16x8*)&Bl[boff + i * 512];
        }
#pragma unroll
        for (int i = 0; i < 4; ++i)
#pragma unroll
            for (int j = 0; j < 4; ++j)
                acc[i][j] = __builtin_amdgcn_mfma_f32_16x16x32_bf16(bq[j], af[i], acc[i][j], 0, 0, 0);
        __syncthreads();
    }

    // Epilogue: vector f32x4 accumulate; lane holds 4 consecutive d-cols.
    const int tcol = lane & 15;
    const int nr0 = (lane >> 4) * 4;
#pragma unroll
    for (int i = 0; i < 4; ++i) {
        const int token = wr * 64 + i * 16 + tcol;
        float* cp = Cacc + (size_t)(m0 + token) * 1024 + n0;
#pragma unroll
        for (int j = 0; j < 4; ++j) {
            const int n = wc * 64 + j * 16 + nr0;
            f32x4 v = acc[i][j];
            if (init) {
                *(f32x4*)(cp + n) = v;
            } else {
                f32x4 old = *(const f32x4*)(cp + n);
                *(f32x4*)(cp + n) = old + v;
            }
        }
    }
}

// ------------- Combine: out = sum_z part[z] + sum_e mw*b2 --------------------
__global__ __launch_bounds__(256) void moe_combine_kernel(
    const float* __restrict__ part, int S,
    float* __restrict__ out, const float* __restrict__ mw,
    const float* __restrict__ b2)
{
    const int n = blockIdx.x, t = threadIdx.x;
    const int d = t * 4;
    f32x4 v = *(const f32x4*)(part + (size_t)n * 1024 + d);
    for (int z = 1; z < S; ++z)
        v = v + *(const f32x4*)(part + (size_t)z * (8192 * 1024) + (size_t)n * 1024 + d);
#pragma unroll
    for (int e = 0; e < 8; ++e) {
        const float w = mw[(size_t)n * 8 + e];
        const f32x4 b = *(const f32x4*)(b2 + (size_t)e * 1024 + d);
        v = v + w * b;
    }
    *(f32x4*)(out + (size_t)n * 1024 + d) = v;
}

extern "C" void kernel_launch(void* const* d_in, const int* in_sizes, int n_in,
                              void* d_out, int out_size, void* d_ws, size_t ws_size,
                              hipStream_t stream)
{
    (void)in_sizes; (void)n_in; (void)out_size;
    const float* h  = (const float*)d_in[0];
    const float* Wr = (const float*)d_in[1];
    const float* br = (const float*)d_in[2];
    const float* W1 = (const float*)d_in[3];
    const float* b1 = (const float*)d_in[4];
    const float* W2 = (const float*)d_in[5];
    const float* b2 = (const float*)d_in[6];
    float* out = (float*)d_out;   // fp32 output [N][D]

    const int N = 8192, D = 1024, F = 4096, E = 8;
    auto al = [](size_t x) { return (x + 255) & ~(size_t)255; };
    const size_t sz_hbf = al((size_t)N * D * 2);
    const size_t sz_mw  = al((size_t)N * E * 4);
    const size_t sz_pt1 = al((size_t)N * D * 4);           // one fp32 partial
    auto tot = [&](int fc, int S, bool full) {
        size_t s = sz_hbf + sz_mw + al((size_t)N * E * fc * 2);
        s += (full ? al((size_t)E * F * D * 2) : al((size_t)E * fc * D * 2)) * 2;
        if (S > 1) s += (size_t)S * sz_pt1;
        return s;
    };
    int Fc, S; bool full;
    if      (tot(1024, 2, true)  <= ws_size) { Fc = 1024; S = 2; full = true;  }
    else if (tot(512,  2, true)  <= ws_size) { Fc = 512;  S = 2; full = true;  }
    else if (tot(1024, 1, true)  <= ws_size) { Fc = 1024; S = 1; full = true;  }
    else if (tot(512,  1, true)  <= ws_size) { Fc = 512;  S = 1; full = true;  }
    else if (tot(512,  1, false) <= ws_size) { Fc = 512;  S = 1; full = false; }
    else if (tot(256,  1, false) <= ws_size) { Fc = 256;  S = 1; full = false; }
    else                                     { Fc = 128;  S = 1; full = false; }
    const int logFc = (Fc == 1024) ? 10 : (Fc == 512) ? 9 : (Fc == 256 ? 8 : 7);

    char* p = (char*)d_ws;
    unsigned short* hbf = (unsigned short*)p; p += sz_hbf;
    float* mwp  = (float*)p; p += sz_mw;
    unsigned short* ghid = (unsigned short*)p; p += al((size_t)N * E * Fc * 2);
    unsigned short* W1t  = (unsigned short*)p;
    p += full ? al((size_t)E * F * D * 2) : al((size_t)E * Fc * D * 2);
    unsigned short* W2t  = (unsigned short*)p;
    p += full ? al((size_t)E * F * D * 2) : al((size_t)E * Fc * D * 2);
    float* part = (S > 1) ? (float*)p : out;   // S==1: accumulate into out

    moe_router_kernel<<<N / 4, 256, 0, stream>>>(h, Wr, br, hbf, mwp);

    if (full) {
        moe_tcvt_kernel<<<dim3(D / 32, F / 32, E), 256, 0, stream>>>(
            W1, W1t, F, (size_t)D * F, D, (size_t)F * D);
        moe_tcvt_kernel<<<dim3(F / 32, D / 32, E), 256, 0, stream>>>(
            W2, W2t, D, (size_t)F * D, F, (size_t)D * F);
    }

    const int nch = F / Fc;
    const int Kc = E * Fc;
    for (int c = 0; c < nch; ++c) {
        if (!full) {
            moe_tcvt_kernel<<<dim3(D / 32, Fc / 32, E), 256, 0, stream>>>(
                W1 + (size_t)c * Fc, W1t, F, (size_t)D * F, D, (size_t)Fc * D);
            moe_tcvt_kernel<<<dim3(Fc / 32, D / 32, E), 256, 0, stream>>>(
                W2 + (size_t)c * Fc * D, W2t, D, (size_t)F * D, Fc, (size_t)D * Fc);
        }
        const unsigned short* B1p = W1t + (full ? (size_t)c * Fc * D : 0);
        const size_t es1 = full ? (size_t)F * D : (size_t)Fc * D;
        moe_gemm1_kernel<<<dim3(N / 128, Kc / 128), 256, 0, stream>>>(
            hbf, B1p, es1, b1, mwp, ghid, Fc, c * Fc);

        const unsigned short* B2p = W2t + (full ? (size_t)c * Fc : 0);
        const size_t es2 = full ? (size_t)D * F : (size_t)D * Fc;
        const int ldb2 = full ? F : Fc;
        moe_gemm2_kernel<<<dim3(N / 128, D / 128, S), 256, 0, stream>>>(
            ghid, B2p, es2, ldb2, part, Kc, Kc / S, logFc, (c == 0) ? 1 : 0);
    }

    moe_combine_kernel<<<N, 256, 0, stream>>>(part, S, out, mwp, b2);
}

// Round 6
// 1525.085 us; speedup vs baseline: 1.3662x; 1.2710x over previous
//
#include <hip/hip_runtime.h>
#include <hip/hip_bf16.h>
#include <cstdint>
#include <cstddef>

typedef __attribute__((ext_vector_type(8))) __bf16 bf16x8;
typedef __attribute__((ext_vector_type(4))) float f32x4;
typedef __attribute__((ext_vector_type(4))) unsigned short us4;

#define GLOAD_LDS16(g, l)                                                        \
    __builtin_amdgcn_global_load_lds(                                            \
        (const __attribute__((address_space(1))) void*)(g),                      \
        (__attribute__((address_space(3))) void*)(l), 16, 0, 0)

static __device__ __forceinline__ unsigned short f2bf(float x) {
    unsigned int u = __builtin_bit_cast(unsigned int, x);
    return (unsigned short)((u + 0x7FFFu + ((u >> 16) & 1u)) >> 16);
}

// gelu(x) = x * sigmoid(1.5957691x + 0.0713548x^3)  (== tanh-form gelu)
static __device__ __forceinline__ float gelu_fast(float x) {
    const float p = x * x;
    const float u = x * fmaf(0.0713548162726f, p, 1.59576912161f);
    const float t = __expf(-u);
    return x * __builtin_amdgcn_rcpf(1.0f + t);
}

// ---------------- Router: logits -> softmax -> mask, plus h -> bf16 ----------
__global__ __launch_bounds__(256) void moe_router_kernel(
    const float* __restrict__ h, const float* __restrict__ Wr,
    const float* __restrict__ br, unsigned short* __restrict__ hbf,
    float* __restrict__ mw)
{
    const int lane = threadIdx.x & 63, wave = threadIdx.x >> 6;
    const int n = blockIdx.x * 4 + wave;  // one token per wave
    const float* hr = h + (size_t)n * 1024;
    const int base = lane * 16;

    float xs[16];
#pragma unroll
    for (int q = 0; q < 4; ++q) {
        f32x4 v = *(const f32x4*)(hr + base + q * 4);
        xs[q * 4 + 0] = v[0]; xs[q * 4 + 1] = v[1];
        xs[q * 4 + 2] = v[2]; xs[q * 4 + 3] = v[3];
    }
    float acc[8] = {0.f, 0.f, 0.f, 0.f, 0.f, 0.f, 0.f, 0.f};
#pragma unroll
    for (int j = 0; j < 16; ++j) {
        const float x = xs[j];
        const f32x4 w0 = *(const f32x4*)(Wr + (size_t)(base + j) * 8);
        const f32x4 w1 = *(const f32x4*)(Wr + (size_t)(base + j) * 8 + 4);
        acc[0] += x * w0[0]; acc[1] += x * w0[1]; acc[2] += x * w0[2]; acc[3] += x * w0[3];
        acc[4] += x * w1[0]; acc[5] += x * w1[1]; acc[6] += x * w1[2]; acc[7] += x * w1[3];
    }
#pragma unroll
    for (int q = 0; q < 4; ++q) {
        us4 o;
        o[0] = f2bf(xs[q * 4 + 0]); o[1] = f2bf(xs[q * 4 + 1]);
        o[2] = f2bf(xs[q * 4 + 2]); o[3] = f2bf(xs[q * 4 + 3]);
        *(us4*)(hbf + (size_t)n * 1024 + base + q * 4) = o;
    }
#pragma unroll
    for (int m = 32; m >= 1; m >>= 1)
#pragma unroll
        for (int e = 0; e < 8; ++e) acc[e] += __shfl_xor(acc[e], m, 64);

    if (lane == 0) {
        float l[8]; float mx = -1e30f;
#pragma unroll
        for (int e = 0; e < 8; ++e) { l[e] = acc[e] + br[e]; mx = fmaxf(mx, l[e]); }
        float s = 0.f;
#pragma unroll
        for (int e = 0; e < 8; ++e) { l[e] = __expf(l[e] - mx); s += l[e]; }
        const float inv = 1.0f / s;
#pragma unroll
        for (int e = 0; e < 8; ++e) {
            const float w = l[e] * inv;
            mw[(size_t)n * 8 + e] = (w > 0.05f) ? w : 0.0f;
        }
    }
}

// ---------- Transpose + fp32->bf16 convert (32x32 tiles, per expert z) -------
__global__ __launch_bounds__(256) void moe_tcvt_kernel(
    const float* __restrict__ in, unsigned short* __restrict__ out,
    int ls, size_t in_es, int os, size_t out_es)
{
    __shared__ unsigned short t[32][33];
    const int e = blockIdx.z;
    const int r = threadIdx.x >> 3, c = (threadIdx.x & 7) * 4;
    const float* I = in + (size_t)e * in_es + (size_t)(blockIdx.x * 32 + r) * ls + blockIdx.y * 32 + c;
    f32x4 v = *(const f32x4*)I;
    t[r][c + 0] = f2bf(v[0]); t[r][c + 1] = f2bf(v[1]);
    t[r][c + 2] = f2bf(v[2]); t[r][c + 3] = f2bf(v[3]);
    __syncthreads();
    unsigned short* O = out + (size_t)e * out_es + (size_t)(blockIdx.y * 32 + r) * os + blockIdx.x * 32 + c;
    us4 o;
    o[0] = t[c + 0][r]; o[1] = t[c + 1][r]; o[2] = t[c + 2][r]; o[3] = t[c + 3][r];
    *(us4*)O = o;
}

// ============ 8-phase 256x256 GEMM (BK=64, 8 waves, dbuf, T2+T3+T4+T5) =======
// MODE 0: ghid = mw * gelu(hbf @ W1t^T + b1)    (bf16 out, pitch ldc)
// MODE 1: part[z] (+)= ghid[:, klo:klo+kspan] @ W2t^T   (fp32 RMW)
// Swapped-operand MFMA (verified R3-R5): acc[i][j] -> m = lane&15,
// n = (lane>>4)*4 + reg.  LDS XOR-swizzle slot^=(row&7) at 16B granule,
// applied to global source (stage) and ds_read; LDS dest stays linear.
#define MFMA_QUAD(MB, NB, AF, BQ)                                              \
  _Pragma("unroll") for (int mi_ = 0; mi_ < 4; ++mi_)                          \
  _Pragma("unroll") for (int ni_ = 0; ni_ < 2; ++ni_) {                        \
      acc[(MB)+mi_][(NB)+ni_] = __builtin_amdgcn_mfma_f32_16x16x32_bf16(       \
          BQ[ni_][1], AF[mi_][1], __builtin_amdgcn_mfma_f32_16x16x32_bf16(     \
          BQ[ni_][0], AF[mi_][0], acc[(MB)+mi_][(NB)+ni_], 0, 0, 0), 0, 0, 0); \
  }

#define PH_MID()  do { __builtin_amdgcn_s_barrier();                           \
    asm volatile("s_waitcnt lgkmcnt(0)" ::: "memory");                         \
    __builtin_amdgcn_sched_barrier(0);                                         \
    __builtin_amdgcn_s_setprio(1); } while (0)
#define PH_ENDQ() do { __builtin_amdgcn_s_setprio(0);                          \
    __builtin_amdgcn_s_barrier(); } while (0)

template <int MODE>
__global__ __launch_bounds__(512) void moe_gemm8p(
    const unsigned short* __restrict__ A, int ldga,
    const unsigned short* __restrict__ Bbase, size_t estride, int ldb,
    const float* __restrict__ b1, const float* __restrict__ mw,
    unsigned short* __restrict__ Cg, int ldc,
    float* __restrict__ part,
    int logFc, int f0glob, int kspan, int init)
{
    __shared__ unsigned short sh[65536];   // 128 KiB: XA,XB,YA,YB (32KB each)
    char* sm = (char*)sh;
    const int XA = 0, XB = 32768, YA = 65536, YB = 98304;

    const int tid = threadIdx.x, lane = tid & 63, wv = tid >> 6;
    const int wr = wv >> 2, wc = wv & 3;

    // XCD-affine bijective block mapping (flat id % 8 == bx-group)
    int bx, by;
    if constexpr (MODE == 0) {
        const int gy = gridDim.y;
        const int orig = blockIdx.x + blockIdx.y * 32;
        const int c8 = orig & 7, j = orig >> 3;       // j in [0, 4*gy)
        bx = c8 * 4 + j / gy; by = j % gy;
    } else {
        const int orig = blockIdx.x + blockIdx.y * 32; // [0,128)
        const int c8 = orig & 7, j = orig >> 3;        // [0,16)
        bx = c8 * 4 + (j >> 2); by = j & 3;
    }
    const int m0 = bx * 256;
    const int n0 = by * 256;

    const int z = (MODE == 1) ? blockIdx.z : 0;
    const int klo = z * kspan;
    float* Cacc = (MODE == 1) ? part + (size_t)z * (8192 * 1024) : nullptr;

    // MODE0 fixed expert / B base
    int e0 = 0, fb = 0;
    const unsigned short* gB0 = nullptr;
    // staging precompute: thread covers rows rl0 (q=0) and rl0+64 (q=1)
    const int rl0 = tid >> 3;
    const int gs8 = ((tid & 7) ^ (rl0 & 7)) * 8;       // XOR-swizzled src col
    if constexpr (MODE == 0) {
        e0 = n0 >> logFc; fb = n0 - (e0 << logFc);
        gB0 = Bbase + (size_t)e0 * estride + (size_t)(fb + rl0) * ldb + gs8;
    }
    const unsigned short* gA0 = A + (size_t)(m0 + rl0) * ldga + gs8;
    const int dstw = wv * 1024;

    auto stage_tile = [&](int regA, int regB, int kk) {
        const unsigned short* ga = gA0 + kk;
        const unsigned short* gb;
        if constexpr (MODE == 0) {
            gb = gB0 + kk;
        } else {
            const int e = kk >> logFc, kc = kk - (e << logFc);
            gb = Bbase + (size_t)e * estride + (size_t)(n0 + rl0) * ldb + kc + gs8;
        }
#pragma unroll
        for (int hf = 0; hf < 2; ++hf)
#pragma unroll
            for (int q = 0; q < 2; ++q) {
                const int rr = hf * 128 + q * 64;
                GLOAD_LDS16(ga + (size_t)rr * ldga, sm + regA + hf * 16384 + q * 8192 + dstw);
                GLOAD_LDS16(gb + (size_t)rr * ldb,  sm + regB + hf * 16384 + q * 8192 + dstw);
            }
    };

    // ds_read swizzled addresses
    const int l15 = lane & 15, l4 = lane >> 4, l7 = lane & 7;
    const int sA0 = (wr * 128 + l15) * 128 + (((0 + l4) ^ l7) << 4);
    const int sA1 = (wr * 128 + l15) * 128 + (((4 + l4) ^ l7) << 4);
    const int sB0 = (wc * 64 + l15) * 128 + (((0 + l4) ^ l7) << 4);
    const int sB1 = (wc * 64 + l15) * 128 + (((4 + l4) ^ l7) << 4);

    f32x4 acc[8][4] = {};
    bf16x8 afL[4][2], afH[4][2], bqL[2][2], bqH[2][2];

#define RD_AFL(BASE) _Pragma("unroll") for (int mi_=0;mi_<4;++mi_){            \
      afL[mi_][0] = *(const bf16x8*)(sm + (BASE) + sA0 + mi_*2048);            \
      afL[mi_][1] = *(const bf16x8*)(sm + (BASE) + sA1 + mi_*2048); }
#define RD_AFH(BASE) _Pragma("unroll") for (int mi_=0;mi_<4;++mi_){            \
      afH[mi_][0] = *(const bf16x8*)(sm + (BASE) + sA0 + (4+mi_)*2048);        \
      afH[mi_][1] = *(const bf16x8*)(sm + (BASE) + sA1 + (4+mi_)*2048); }
#define RD_BQL(BASE) _Pragma("unroll") for (int ni_=0;ni_<2;++ni_){            \
      bqL[ni_][0] = *(const bf16x8*)(sm + (BASE) + sB0 + ni_*2048);            \
      bqL[ni_][1] = *(const bf16x8*)(sm + (BASE) + sB1 + ni_*2048); }
#define RD_BQH(BASE) _Pragma("unroll") for (int ni_=0;ni_<2;++ni_){            \
      bqH[ni_][0] = *(const bf16x8*)(sm + (BASE) + sB0 + (2+ni_)*2048);        \
      bqH[ni_][1] = *(const bf16x8*)(sm + (BASE) + sB1 + (2+ni_)*2048); }

    const int niter = kspan >> 7;  // 2 K-tiles (2x64) per iteration

    // Prologue: stage tiles 0 (X) and 1 (Y); wait X landed (Y stays in flight)
    stage_tile(XA, XB, klo);
    stage_tile(YA, YB, klo + 64);
    asm volatile("s_waitcnt vmcnt(8)" ::: "memory");
    __builtin_amdgcn_sched_barrier(0);
    __builtin_amdgcn_s_barrier();

    for (int it = 0; it < niter; ++it) {
        const int kkX = klo + it * 128;
        const bool g = (it + 1 < niter);
        // ---- X half (tile 2it) ----
        RD_AFL(XA); RD_BQL(XB);
        PH_MID(); MFMA_QUAD(0, 0, afL, bqL); PH_ENDQ();
        RD_BQH(XB);
        PH_MID(); MFMA_QUAD(0, 2, afL, bqH); PH_ENDQ();
        RD_AFH(XA);
        PH_MID(); MFMA_QUAD(4, 0, afH, bqL); PH_ENDQ();
        // P4: stage next X-tile (X fully consumed at P3); drain Y for P5
        if (g) { stage_tile(XA, XB, kkX + 128);
                 asm volatile("s_waitcnt vmcnt(8)" ::: "memory"); }
        else   { asm volatile("s_waitcnt vmcnt(0)" ::: "memory"); }
        __builtin_amdgcn_sched_barrier(0);
        __builtin_amdgcn_s_barrier();
        __builtin_amdgcn_s_setprio(1);
        MFMA_QUAD(4, 2, afH, bqH);
        PH_ENDQ();
        // ---- Y half (tile 2it+1) ----
        RD_AFL(YA); RD_BQL(YB);
        PH_MID(); MFMA_QUAD(0, 0, afL, bqL); PH_ENDQ();
        RD_BQH(YB);
        PH_MID(); MFMA_QUAD(0, 2, afL, bqH); PH_ENDQ();
        RD_AFH(YA);
        PH_MID(); MFMA_QUAD(4, 0, afH, bqL); PH_ENDQ();
        // P8: stage next Y-tile; drain X for next-iter P1
        if (g) { stage_tile(YA, YB, kkX + 192);
                 asm volatile("s_waitcnt vmcnt(8)" ::: "memory"); }
        else   { asm volatile("s_waitcnt vmcnt(0)" ::: "memory"); }
        __builtin_amdgcn_sched_barrier(0);
        __builtin_amdgcn_s_barrier();
        __builtin_amdgcn_s_setprio(1);
        MFMA_QUAD(4, 2, afH, bqH);
        PH_ENDQ();
    }

    // Epilogue
    const int nr0v = l4 * 4;
    if constexpr (MODE == 0) {
        const float* b1p = b1 + (size_t)e0 * 4096 + f0glob + fb;
        f32x4 b1v[4];
#pragma unroll
        for (int j = 0; j < 4; ++j)
            b1v[j] = *(const f32x4*)(b1p + wc * 64 + j * 16 + nr0v);
#pragma unroll
        for (int i = 0; i < 8; ++i) {
            const int token = m0 + wr * 128 + i * 16 + l15;
            const float w = mw[(size_t)token * 8 + e0];
            unsigned short* crow = Cg + (size_t)token * ldc + n0;
#pragma unroll
            for (int j = 0; j < 4; ++j) {
                const int n = wc * 64 + j * 16 + nr0v;
                us4 o;
#pragma unroll
                for (int r = 0; r < 4; ++r)
                    o[r] = f2bf(w * gelu_fast(acc[i][j][r] + b1v[j][r]));
                *(us4*)(crow + n) = o;
            }
        }
    } else {
#pragma unroll
        for (int i = 0; i < 8; ++i) {
            const int row = m0 + wr * 128 + i * 16 + l15;
            float* cp = Cacc + (size_t)row * 1024 + n0;
#pragma unroll
            for (int j = 0; j < 4; ++j) {
                const int n = wc * 64 + j * 16 + nr0v;
                if (init) {
                    *(f32x4*)(cp + n) = acc[i][j];
                } else {
                    f32x4 old = *(const f32x4*)(cp + n);
                    *(f32x4*)(cp + n) = old + acc[i][j];
                }
            }
        }
    }
}

// ------------- Combine: out = sum_z part[z] + sum_e mw*b2 --------------------
__global__ __launch_bounds__(256) void moe_combine_kernel(
    const float* __restrict__ part, int S,
    float* __restrict__ out, const float* __restrict__ mw,
    const float* __restrict__ b2)
{
    const int n = blockIdx.x, t = threadIdx.x;
    const int d = t * 4;
    f32x4 v = *(const f32x4*)(part + (size_t)n * 1024 + d);
    for (int z = 1; z < S; ++z)
        v = v + *(const f32x4*)(part + (size_t)z * (8192 * 1024) + (size_t)n * 1024 + d);
#pragma unroll
    for (int e = 0; e < 8; ++e) {
        const float w = mw[(size_t)n * 8 + e];
        const f32x4 b = *(const f32x4*)(b2 + (size_t)e * 1024 + d);
        v = v + w * b;
    }
    *(f32x4*)(out + (size_t)n * 1024 + d) = v;
}

extern "C" void kernel_launch(void* const* d_in, const int* in_sizes, int n_in,
                              void* d_out, int out_size, void* d_ws, size_t ws_size,
                              hipStream_t stream)
{
    (void)in_sizes; (void)n_in; (void)out_size;
    const float* h  = (const float*)d_in[0];
    const float* Wr = (const float*)d_in[1];
    const float* br = (const float*)d_in[2];
    const float* W1 = (const float*)d_in[3];
    const float* b1 = (const float*)d_in[4];
    const float* W2 = (const float*)d_in[5];
    const float* b2 = (const float*)d_in[6];
    float* out = (float*)d_out;   // fp32 output [N][D]

    const int N = 8192, D = 1024, F = 4096, E = 8;
    const int S = 2;
    auto al = [](size_t x) { return (x + 255) & ~(size_t)255; };
    const size_t sz_hbf = al((size_t)N * D * 2);
    const size_t sz_mw  = al((size_t)N * E * 4);
    const size_t sz_pt1 = al((size_t)N * D * 4);
    auto tot = [&](int fc, bool full) {
        size_t s = sz_hbf + sz_mw + al((size_t)N * ((size_t)E * fc + 64) * 2);
        s += (full ? al((size_t)E * F * D * 2) : al((size_t)E * fc * D * 2)) * 2;
        s += (size_t)S * sz_pt1;
        return s;
    };
    int Fc; bool full;
    if      (tot(512, true)  <= ws_size) { Fc = 512; full = true;  }
    else if (tot(512, false) <= ws_size) { Fc = 512; full = false; }
    else                                 { Fc = 256; full = false; }
    const int logFc = (Fc == 512) ? 9 : 8;
    const int Kc = E * Fc;
    const int ldAp = Kc + 64;   // padded ghid pitch (breaks pow2 row alias)

    char* p = (char*)d_ws;
    unsigned short* hbf = (unsigned short*)p; p += sz_hbf;
    float* mwp  = (float*)p; p += sz_mw;
    unsigned short* ghid = (unsigned short*)p; p += al((size_t)N * (size_t)ldAp * 2);
    unsigned short* W1t  = (unsigned short*)p;
    p += full ? al((size_t)E * F * D * 2) : al((size_t)E * Fc * D * 2);
    unsigned short* W2t  = (unsigned short*)p;
    p += full ? al((size_t)E * F * D * 2) : al((size_t)E * Fc * D * 2);
    float* part = (float*)p;

    moe_router_kernel<<<N / 4, 256, 0, stream>>>(h, Wr, br, hbf, mwp);

    if (full) {
        moe_tcvt_kernel<<<dim3(D / 32, F / 32, E), 256, 0, stream>>>(
            W1, W1t, F, (size_t)D * F, D, (size_t)F * D);
        moe_tcvt_kernel<<<dim3(F / 32, D / 32, E), 256, 0, stream>>>(
            W2, W2t, D, (size_t)F * D, F, (size_t)D * F);
    }

    const int nch = F / Fc;
    for (int c = 0; c < nch; ++c) {
        if (!full) {
            moe_tcvt_kernel<<<dim3(D / 32, Fc / 32, E), 256, 0, stream>>>(
                W1 + (size_t)c * Fc, W1t, F, (size_t)D * F, D, (size_t)Fc * D);
            moe_tcvt_kernel<<<dim3(Fc / 32, D / 32, E), 256, 0, stream>>>(
                W2 + (size_t)c * Fc * D, W2t, D, (size_t)F * D, Fc, (size_t)D * Fc);
        }
        const unsigned short* B1p = W1t + (full ? (size_t)c * Fc * D : 0);
        const size_t es1 = full ? (size_t)F * D : (size_t)Fc * D;
        moe_gemm8p<0><<<dim3(32, Kc / 256, 1), 512, 0, stream>>>(
            hbf, 1024, B1p, es1, 1024, b1, mwp, ghid, ldAp, nullptr,
            logFc, c * Fc, /*kspan=*/1024, 0);

        const unsigned short* B2p = W2t + (full ? (size_t)c * Fc : 0);
        const size_t es2 = full ? (size_t)D * F : (size_t)D * Fc;
        const int ldb2 = full ? F : Fc;
        moe_gemm8p<1><<<dim3(32, 4, S), 512, 0, stream>>>(
            ghid, ldAp, B2p, es2, ldb2, nullptr, nullptr, nullptr, 0, part,
            logFc, 0, /*kspan=*/Kc / S, (c == 0) ? 1 : 0);
    }

    moe_combine_kernel<<<N, 256, 0, stream>>>(part, S, out, mwp, b2);
}

// Round 7
// 1359.300 us; speedup vs baseline: 1.5328x; 1.1220x over previous
//
#include <hip/hip_runtime.h>
#include <hip/hip_bf16.h>
#include <cstdint>
#include <cstddef>

typedef __attribute__((ext_vector_type(8))) __bf16 bf16x8;
typedef __attribute__((ext_vector_type(4))) float f32x4;
typedef __attribute__((ext_vector_type(4))) unsigned short us4;

#define GLOAD_LDS16(g, l)                                                        \
    __builtin_amdgcn_global_load_lds(                                            \
        (const __attribute__((address_space(1))) void*)(g),                      \
        (__attribute__((address_space(3))) void*)(l), 16, 0, 0)

static __device__ __forceinline__ unsigned short f2bf(float x) {
    unsigned int u = __builtin_bit_cast(unsigned int, x);
    return (unsigned short)((u + 0x7FFFu + ((u >> 16) & 1u)) >> 16);
}

// gelu(x) = x * sigmoid(1.5957691x + 0.0713548x^3)  (== tanh-form gelu)
static __device__ __forceinline__ float gelu_fast(float x) {
    const float p = x * x;
    const float u = x * fmaf(0.0713548162726f, p, 1.59576912161f);
    const float t = __expf(-u);
    return x * __builtin_amdgcn_rcpf(1.0f + t);
}

// ---------------- Router: logits -> softmax -> mask, plus h -> bf16 ----------
__global__ __launch_bounds__(256) void moe_router_kernel(
    const float* __restrict__ h, const float* __restrict__ Wr,
    const float* __restrict__ br, unsigned short* __restrict__ hbf,
    float* __restrict__ mw)
{
    const int lane = threadIdx.x & 63, wave = threadIdx.x >> 6;
    const int n = blockIdx.x * 4 + wave;  // one token per wave
    const float* hr = h + (size_t)n * 1024;
    const int base = lane * 16;

    float xs[16];
#pragma unroll
    for (int q = 0; q < 4; ++q) {
        f32x4 v = *(const f32x4*)(hr + base + q * 4);
        xs[q * 4 + 0] = v[0]; xs[q * 4 + 1] = v[1];
        xs[q * 4 + 2] = v[2]; xs[q * 4 + 3] = v[3];
    }
    float acc[8] = {0.f, 0.f, 0.f, 0.f, 0.f, 0.f, 0.f, 0.f};
#pragma unroll
    for (int j = 0; j < 16; ++j) {
        const float x = xs[j];
        const f32x4 w0 = *(const f32x4*)(Wr + (size_t)(base + j) * 8);
        const f32x4 w1 = *(const f32x4*)(Wr + (size_t)(base + j) * 8 + 4);
        acc[0] += x * w0[0]; acc[1] += x * w0[1]; acc[2] += x * w0[2]; acc[3] += x * w0[3];
        acc[4] += x * w1[0]; acc[5] += x * w1[1]; acc[6] += x * w1[2]; acc[7] += x * w1[3];
    }
#pragma unroll
    for (int q = 0; q < 4; ++q) {
        us4 o;
        o[0] = f2bf(xs[q * 4 + 0]); o[1] = f2bf(xs[q * 4 + 1]);
        o[2] = f2bf(xs[q * 4 + 2]); o[3] = f2bf(xs[q * 4 + 3]);
        *(us4*)(hbf + (size_t)n * 1024 + base + q * 4) = o;
    }
#pragma unroll
    for (int m = 32; m >= 1; m >>= 1)
#pragma unroll
        for (int e = 0; e < 8; ++e) acc[e] += __shfl_xor(acc[e], m, 64);

    if (lane == 0) {
        float l[8]; float mx = -1e30f;
#pragma unroll
        for (int e = 0; e < 8; ++e) { l[e] = acc[e] + br[e]; mx = fmaxf(mx, l[e]); }
        float s = 0.f;
#pragma unroll
        for (int e = 0; e < 8; ++e) { l[e] = __expf(l[e] - mx); s += l[e]; }
        const float inv = 1.0f / s;
#pragma unroll
        for (int e = 0; e < 8; ++e) {
            const float w = l[e] * inv;
            mw[(size_t)n * 8 + e] = (w > 0.05f) ? w : 0.0f;
        }
    }
}

// ---------- Transpose + fp32->bf16 convert (32x32 tiles, per expert z) -------
__global__ __launch_bounds__(256) void moe_tcvt_kernel(
    const float* __restrict__ in, unsigned short* __restrict__ out,
    int ls, size_t in_es, int os, size_t out_es)
{
    __shared__ unsigned short t[32][33];
    const int e = blockIdx.z;
    const int r = threadIdx.x >> 3, c = (threadIdx.x & 7) * 4;
    const float* I = in + (size_t)e * in_es + (size_t)(blockIdx.x * 32 + r) * ls + blockIdx.y * 32 + c;
    f32x4 v = *(const f32x4*)I;
    t[r][c + 0] = f2bf(v[0]); t[r][c + 1] = f2bf(v[1]);
    t[r][c + 2] = f2bf(v[2]); t[r][c + 3] = f2bf(v[3]);
    __syncthreads();
    unsigned short* O = out + (size_t)e * out_es + (size_t)(blockIdx.y * 32 + r) * os + blockIdx.x * 32 + c;
    us4 o;
    o[0] = t[c + 0][r]; o[1] = t[c + 1][r]; o[2] = t[c + 2][r]; o[3] = t[c + 3][r];
    *(us4*)O = o;
}

// ============ 8-phase 256x256 GEMM, BK=64, look-ahead ds_read pipeline =======
// MODE 0: ghid = mw * gelu(hbf @ W1t^T + b1)    (bf16 out, pitch ldc)
// MODE 1: part[z] (+)= ghid[:, klo:klo+kspan] @ W2t^T   (fp32 RMW)
// Quadrant rotation Q1(afL,bqL) Q2(afL,bqH) Q3(afH,bqL) Q4(afH,bqH);
// phase p issues ds_reads for phase p+1, waits lgkmcnt(<just-issued>).
// Staging spread P2/P3/P4 (P6/P7/P8), each region only after its readers'
// global-done barrier chain.  vmcnt(8) before P4/P8 barrier; cross-buffer
// Q1 reads after that barrier.
#define MFMA_QUAD(MB, NB, AF, BQ)                                              \
  _Pragma("unroll") for (int mi_ = 0; mi_ < 4; ++mi_)                          \
  _Pragma("unroll") for (int ni_ = 0; ni_ < 2; ++ni_) {                        \
      acc[(MB)+mi_][(NB)+ni_] = __builtin_amdgcn_mfma_f32_16x16x32_bf16(       \
          BQ[ni_][1], AF[mi_][1], __builtin_amdgcn_mfma_f32_16x16x32_bf16(     \
          BQ[ni_][0], AF[mi_][0], acc[(MB)+mi_][(NB)+ni_], 0, 0, 0), 0, 0, 0); \
  }

#define BARX()   __builtin_amdgcn_s_barrier()
#define SBX()    __builtin_amdgcn_sched_barrier(0)
#define LGKM(N)  asm volatile("s_waitcnt lgkmcnt(" #N ")" ::: "memory")
#define VMC(N)   asm volatile("s_waitcnt vmcnt(" #N ")" ::: "memory")
#define PRIO1()  __builtin_amdgcn_s_setprio(1)
#define PRIO0()  __builtin_amdgcn_s_setprio(0)

template <int MODE>
__global__ __launch_bounds__(512) void moe_gemm8p(
    const unsigned short* __restrict__ A, int ldga,
    const unsigned short* __restrict__ Bbase, size_t estride, int ldb,
    const float* __restrict__ b1, const float* __restrict__ mw,
    unsigned short* __restrict__ Cg, int ldc,
    float* __restrict__ part,
    int logFc, int f0glob, int kspan, int init)
{
    __shared__ unsigned short sh[65536];   // 128 KiB: XA,XB,YA,YB (32KB each)
    char* sm = (char*)sh;
    const int XA = 0, XB = 32768, YA = 65536, YB = 98304;

    const int tid = threadIdx.x, lane = tid & 63, wv = tid >> 6;
    const int wr = wv >> 2, wc = wv & 3;

    // XCD-affine bijective block mapping (flat id % 8 == bx-group)
    int bx, by;
    if constexpr (MODE == 0) {
        const int gy = gridDim.y;
        const int orig = blockIdx.x + blockIdx.y * 32;
        const int c8 = orig & 7, j = orig >> 3;       // j in [0, 4*gy)
        bx = c8 * 4 + j / gy; by = j % gy;
    } else {
        const int orig = blockIdx.x + blockIdx.y * 32; // [0,128)
        const int c8 = orig & 7, j = orig >> 3;        // [0,16)
        bx = c8 * 4 + (j >> 2); by = j & 3;
    }
    const int m0 = bx * 256;
    const int n0 = by * 256;

    const int z = (MODE == 1) ? blockIdx.z : 0;
    const int klo = z * kspan;
    float* Cacc = (MODE == 1) ? part + (size_t)z * (8192 * 1024) : nullptr;

    // MODE0 fixed expert / B base
    int e0 = 0, fb = 0;
    const unsigned short* gB0 = nullptr;
    const int rl0 = tid >> 3;                          // row [0,64)
    const int gs8 = ((tid & 7) ^ (rl0 & 7)) * 8;       // XOR-swizzled src col
    if constexpr (MODE == 0) {
        e0 = n0 >> logFc; fb = n0 - (e0 << logFc);
        gB0 = Bbase + (size_t)e0 * estride + (size_t)(fb + rl0) * ldb + gs8;
    }
    const unsigned short* gA0 = A + (size_t)(m0 + rl0) * ldga + gs8;
    const int dstw = wv * 1024;

    auto stageA = [&](int reg, int kk, int q) {
        GLOAD_LDS16(gA0 + kk + (size_t)(q * 64) * ldga,
                    sm + reg + (q >> 1) * 16384 + (q & 1) * 8192 + dstw);
    };
    auto stageB = [&](int reg, int kk, int q) {
        const unsigned short* gb;
        if constexpr (MODE == 0) {
            gb = gB0 + kk;
        } else {
            const int e = kk >> logFc, kc = kk - (e << logFc);
            gb = Bbase + (size_t)e * estride + (size_t)(n0 + rl0) * ldb + kc + gs8;
        }
        GLOAD_LDS16(gb + (size_t)(q * 64) * ldb,
                    sm + reg + (q >> 1) * 16384 + (q & 1) * 8192 + dstw);
    };

    // ds_read swizzled addresses
    const int l15 = lane & 15, l4 = lane >> 4, l7 = lane & 7;
    const int sA0 = (wr * 128 + l15) * 128 + (((0 + l4) ^ l7) << 4);
    const int sA1 = (wr * 128 + l15) * 128 + (((4 + l4) ^ l7) << 4);
    const int sB0 = (wc * 64 + l15) * 128 + (((0 + l4) ^ l7) << 4);
    const int sB1 = (wc * 64 + l15) * 128 + (((4 + l4) ^ l7) << 4);

    f32x4 acc[8][4] = {};
    bf16x8 afL[4][2], afH[4][2], bqL[2][2], bqH[2][2];

#define RD_AFL(BASE) _Pragma("unroll") for (int mi_=0;mi_<4;++mi_){            \
      afL[mi_][0] = *(const bf16x8*)(sm + (BASE) + sA0 + mi_*2048);            \
      afL[mi_][1] = *(const bf16x8*)(sm + (BASE) + sA1 + mi_*2048); }
#define RD_AFH(BASE) _Pragma("unroll") for (int mi_=0;mi_<4;++mi_){            \
      afH[mi_][0] = *(const bf16x8*)(sm + (BASE) + sA0 + (4+mi_)*2048);        \
      afH[mi_][1] = *(const bf16x8*)(sm + (BASE) + sA1 + (4+mi_)*2048); }
#define RD_BQL(BASE) _Pragma("unroll") for (int ni_=0;ni_<2;++ni_){            \
      bqL[ni_][0] = *(const bf16x8*)(sm + (BASE) + sB0 + ni_*2048);            \
      bqL[ni_][1] = *(const bf16x8*)(sm + (BASE) + sB1 + ni_*2048); }
#define RD_BQH(BASE) _Pragma("unroll") for (int ni_=0;ni_<2;++ni_){            \
      bqH[ni_][0] = *(const bf16x8*)(sm + (BASE) + sB0 + (2+ni_)*2048);        \
      bqH[ni_][1] = *(const bf16x8*)(sm + (BASE) + sB1 + (2+ni_)*2048); }

    const int niter = kspan >> 7;  // 2 K-tiles (2x64) per iteration

    // Prologue: stage X(t0), Y(t1); drain X; read X Q1 frags after barrier.
#pragma unroll
    for (int q = 0; q < 4; ++q) { stageA(XA, klo, q); stageB(XB, klo, q); }
#pragma unroll
    for (int q = 0; q < 4; ++q) { stageA(YA, klo + 64, q); stageB(YB, klo + 64, q); }
    VMC(8); SBX();
    BARX();
    RD_AFL(XA); RD_BQL(XB);

    for (int it = 0; it < niter; ++it) {
        const int kX2 = klo + it * 128 + 128;  // next X tile
        const int kY2 = klo + it * 128 + 192;  // next Y tile
        const bool g = (it + 1 < niter);
        // ---- P1: MFMA Q1(X); read-ahead bqH(X)
        RD_BQH(XB);
        BARX(); LGKM(4); SBX(); PRIO1(); MFMA_QUAD(0, 0, afL, bqL); PRIO0(); BARX();
        // ---- P2: MFMA Q2(X); read-ahead afH(X); stage nextX A q0,q2
        RD_AFH(XA);
        if (g) { stageA(XA, kX2, 0); stageA(XA, kX2, 2); }
        BARX(); LGKM(8); SBX(); PRIO1(); MFMA_QUAD(0, 2, afL, bqH); PRIO0(); BARX();
        // ---- P3: MFMA Q3(X); stage nextX B q0,q1
        if (g) { stageB(XB, kX2, 0); stageB(XB, kX2, 1); }
        BARX(); LGKM(0); SBX(); PRIO1(); MFMA_QUAD(4, 0, afH, bqL); PRIO0(); BARX();
        // ---- P4: stage nextX rest; vmcnt; barrier; read Y Q1; MFMA Q4(X)
        if (g) { stageA(XA, kX2, 1); stageA(XA, kX2, 3);
                 stageB(XB, kX2, 2); stageB(XB, kX2, 3);
                 VMC(8); } else { VMC(0); }
        SBX();
        BARX();
        RD_AFL(YA); RD_BQL(YB);
        SBX(); PRIO1(); MFMA_QUAD(4, 2, afH, bqH); PRIO0(); BARX();
        // ---- P5: MFMA Q1(Y); read-ahead bqH(Y)
        RD_BQH(YB);
        BARX(); LGKM(4); SBX(); PRIO1(); MFMA_QUAD(0, 0, afL, bqL); PRIO0(); BARX();
        // ---- P6: MFMA Q2(Y); read-ahead afH(Y); stage nextY A q0,q2
        RD_AFH(YA);
        if (g) { stageA(YA, kY2, 0); stageA(YA, kY2, 2); }
        BARX(); LGKM(8); SBX(); PRIO1(); MFMA_QUAD(0, 2, afL, bqH); PRIO0(); BARX();
        // ---- P7: MFMA Q3(Y); stage nextY B q0,q1
        if (g) { stageB(YB, kY2, 0); stageB(YB, kY2, 1); }
        BARX(); LGKM(0); SBX(); PRIO1(); MFMA_QUAD(4, 0, afH, bqL); PRIO0(); BARX();
        // ---- P8: stage nextY rest; vmcnt; barrier; read nextX Q1; MFMA Q4(Y)
        if (g) { stageA(YA, kY2, 1); stageA(YA, kY2, 3);
                 stageB(YB, kY2, 2); stageB(YB, kY2, 3);
                 VMC(8); } else { VMC(0); }
        SBX();
        BARX();
        if (g) { RD_AFL(XA); RD_BQL(XB); }
        SBX(); PRIO1(); MFMA_QUAD(4, 2, afH, bqH); PRIO0(); BARX();
    }

    // Epilogue
    const int nr0v = l4 * 4;
    if constexpr (MODE == 0) {
        const float* b1p = b1 + (size_t)e0 * 4096 + f0glob + fb;
        f32x4 b1v[4];
#pragma unroll
        for (int j = 0; j < 4; ++j)
            b1v[j] = *(const f32x4*)(b1p + wc * 64 + j * 16 + nr0v);
#pragma unroll
        for (int i = 0; i < 8; ++i) {
            const int token = m0 + wr * 128 + i * 16 + l15;
            const float w = mw[(size_t)token * 8 + e0];
            unsigned short* crow = Cg + (size_t)token * ldc + n0;
#pragma unroll
            for (int j = 0; j < 4; ++j) {
                const int n = wc * 64 + j * 16 + nr0v;
                us4 o;
#pragma unroll
                for (int r = 0; r < 4; ++r)
                    o[r] = f2bf(w * gelu_fast(acc[i][j][r] + b1v[j][r]));
                *(us4*)(crow + n) = o;
            }
        }
    } else {
#pragma unroll
        for (int i = 0; i < 8; ++i) {
            const int row = m0 + wr * 128 + i * 16 + l15;
            float* cp = Cacc + (size_t)row * 1024 + n0;
#pragma unroll
            for (int j = 0; j < 4; ++j) {
                const int n = wc * 64 + j * 16 + nr0v;
                if (init) {
                    *(f32x4*)(cp + n) = acc[i][j];
                } else {
                    f32x4 old = *(const f32x4*)(cp + n);
                    *(f32x4*)(cp + n) = old + acc[i][j];
                }
            }
        }
    }
}

// ------------- Combine: out = sum_z part[z] + sum_e mw*b2 --------------------
__global__ __launch_bounds__(256) void moe_combine_kernel(
    const float* __restrict__ part, int S,
    float* __restrict__ out, const float* __restrict__ mw,
    const float* __restrict__ b2)
{
    const int n = blockIdx.x, t = threadIdx.x;
    const int d = t * 4;
    f32x4 v = *(const f32x4*)(part + (size_t)n * 1024 + d);
    for (int z = 1; z < S; ++z)
        v = v + *(const f32x4*)(part + (size_t)z * (8192 * 1024) + (size_t)n * 1024 + d);
#pragma unroll
    for (int e = 0; e < 8; ++e) {
        const float w = mw[(size_t)n * 8 + e];
        const f32x4 b = *(const f32x4*)(b2 + (size_t)e * 1024 + d);
        v = v + w * b;
    }
    *(f32x4*)(out + (size_t)n * 1024 + d) = v;
}

extern "C" void kernel_launch(void* const* d_in, const int* in_sizes, int n_in,
                              void* d_out, int out_size, void* d_ws, size_t ws_size,
                              hipStream_t stream)
{
    (void)in_sizes; (void)n_in; (void)out_size;
    const float* h  = (const float*)d_in[0];
    const float* Wr = (const float*)d_in[1];
    const float* br = (const float*)d_in[2];
    const float* W1 = (const float*)d_in[3];
    const float* b1 = (const float*)d_in[4];
    const float* W2 = (const float*)d_in[5];
    const float* b2 = (const float*)d_in[6];
    float* out = (float*)d_out;   // fp32 output [N][D]

    const int N = 8192, D = 1024, F = 4096, E = 8;
    const int S = 2;
    auto al = [](size_t x) { return (x + 255) & ~(size_t)255; };
    const size_t sz_hbf = al((size_t)N * D * 2);
    const size_t sz_mw  = al((size_t)N * E * 4);
    const size_t sz_pt1 = al((size_t)N * D * 4);
    auto tot = [&](int fc, bool full) {
        size_t s = sz_hbf + sz_mw + al((size_t)N * ((size_t)E * fc + 64) * 2);
        s += (full ? al((size_t)E * F * D * 2) : al((size_t)E * fc * D * 2)) * 2;
        s += (size_t)S * sz_pt1;
        return s;
    };
    int Fc; bool full;
    if      (tot(512, true)  <= ws_size) { Fc = 512; full = true;  }
    else if (tot(512, false) <= ws_size) { Fc = 512; full = false; }
    else                                 { Fc = 256; full = false; }
    const int logFc = (Fc == 512) ? 9 : 8;
    const int Kc = E * Fc;
    const int ldAp = Kc + 64;   // padded ghid pitch (breaks pow2 row alias)

    char* p = (char*)d_ws;
    unsigned short* hbf = (unsigned short*)p; p += sz_hbf;
    float* mwp  = (float*)p; p += sz_mw;
    unsigned short* ghid = (unsigned short*)p; p += al((size_t)N * (size_t)ldAp * 2);
    unsigned short* W1t  = (unsigned short*)p;
    p += full ? al((size_t)E * F * D * 2) : al((size_t)E * Fc * D * 2);
    unsigned short* W2t  = (unsigned short*)p;
    p += full ? al((size_t)E * F * D * 2) : al((size_t)E * Fc * D * 2);
    float* part = (float*)p;

    moe_router_kernel<<<N / 4, 256, 0, stream>>>(h, Wr, br, hbf, mwp);

    if (full) {
        moe_tcvt_kernel<<<dim3(D / 32, F / 32, E), 256, 0, stream>>>(
            W1, W1t, F, (size_t)D * F, D, (size_t)F * D);
        moe_tcvt_kernel<<<dim3(F / 32, D / 32, E), 256, 0, stream>>>(
            W2, W2t, D, (size_t)F * D, F, (size_t)D * F);
    }

    const int nch = F / Fc;
    for (int c = 0; c < nch; ++c) {
        if (!full) {
            moe_tcvt_kernel<<<dim3(D / 32, Fc / 32, E), 256, 0, stream>>>(
                W1 + (size_t)c * Fc, W1t, F, (size_t)D * F, D, (size_t)Fc * D);
            moe_tcvt_kernel<<<dim3(Fc / 32, D / 32, E), 256, 0, stream>>>(
                W2 + (size_t)c * Fc * D, W2t, D, (size_t)F * D, Fc, (size_t)D * Fc);
        }
        const unsigned short* B1p = W1t + (full ? (size_t)c * Fc * D : 0);
        const size_t es1 = full ? (size_t)F * D : (size_t)Fc * D;
        moe_gemm8p<0><<<dim3(32, Kc / 256, 1), 512, 0, stream>>>(
            hbf, 1024, B1p, es1, 1024, b1, mwp, ghid, ldAp, nullptr,
            logFc, c * Fc, /*kspan=*/1024, 0);

        const unsigned short* B2p = W2t + (full ? (size_t)c * Fc : 0);
        const size_t es2 = full ? (size_t)D * F : (size_t)D * Fc;
        const int ldb2 = full ? F : Fc;
        moe_gemm8p<1><<<dim3(32, 4, S), 512, 0, stream>>>(
            ghid, ldAp, B2p, es2, ldb2, nullptr, nullptr, nullptr, 0, part,
            logFc, 0, /*kspan=*/Kc / S, (c == 0) ? 1 : 0);
    }

    moe_combine_kernel<<<N, 256, 0, stream>>>(part, S, out, mwp, b2);
}

// Round 8
// 1265.695 us; speedup vs baseline: 1.6462x; 1.0740x over previous
//
#include <hip/hip_runtime.h>
#include <hip/hip_bf16.h>
#include <cstdint>
#include <cstddef>

typedef __attribute__((ext_vector_type(8))) __bf16 bf16x8;
typedef __attribute__((ext_vector_type(4))) float f32x4;
typedef __attribute__((ext_vector_type(4))) unsigned short us4;

#define GLOAD_LDS16(g, l)                                                        \
    __builtin_amdgcn_global_load_lds(                                            \
        (const __attribute__((address_space(1))) void*)(g),                      \
        (__attribute__((address_space(3))) void*)(l), 16, 0, 0)

static __device__ __forceinline__ unsigned short f2bf(float x) {
    unsigned int u = __builtin_bit_cast(unsigned int, x);
    return (unsigned short)((u + 0x7FFFu + ((u >> 16) & 1u)) >> 16);
}

// gelu(x) = x * sigmoid(1.5957691x + 0.0713548x^3)  (== tanh-form gelu)
static __device__ __forceinline__ float gelu_fast(float x) {
    const float p = x * x;
    const float u = x * fmaf(0.0713548162726f, p, 1.59576912161f);
    const float t = __expf(-u);
    return x * __builtin_amdgcn_rcpf(1.0f + t);
}

// ---------------- Router: logits -> softmax -> mask, plus h -> bf16 ----------
__global__ __launch_bounds__(256) void moe_router_kernel(
    const float* __restrict__ h, const float* __restrict__ Wr,
    const float* __restrict__ br, unsigned short* __restrict__ hbf,
    float* __restrict__ mw)
{
    const int lane = threadIdx.x & 63, wave = threadIdx.x >> 6;
    const int n = blockIdx.x * 4 + wave;  // one token per wave
    const float* hr = h + (size_t)n * 1024;
    const int base = lane * 16;

    float xs[16];
#pragma unroll
    for (int q = 0; q < 4; ++q) {
        f32x4 v = *(const f32x4*)(hr + base + q * 4);
        xs[q * 4 + 0] = v[0]; xs[q * 4 + 1] = v[1];
        xs[q * 4 + 2] = v[2]; xs[q * 4 + 3] = v[3];
    }
    float acc[8] = {0.f, 0.f, 0.f, 0.f, 0.f, 0.f, 0.f, 0.f};
#pragma unroll
    for (int j = 0; j < 16; ++j) {
        const float x = xs[j];
        const f32x4 w0 = *(const f32x4*)(Wr + (size_t)(base + j) * 8);
        const f32x4 w1 = *(const f32x4*)(Wr + (size_t)(base + j) * 8 + 4);
        acc[0] += x * w0[0]; acc[1] += x * w0[1]; acc[2] += x * w0[2]; acc[3] += x * w0[3];
        acc[4] += x * w1[0]; acc[5] += x * w1[1]; acc[6] += x * w1[2]; acc[7] += x * w1[3];
    }
#pragma unroll
    for (int q = 0; q < 4; ++q) {
        us4 o;
        o[0] = f2bf(xs[q * 4 + 0]); o[1] = f2bf(xs[q * 4 + 1]);
        o[2] = f2bf(xs[q * 4 + 2]); o[3] = f2bf(xs[q * 4 + 3]);
        *(us4*)(hbf + (size_t)n * 1024 + base + q * 4) = o;
    }
#pragma unroll
    for (int m = 32; m >= 1; m >>= 1)
#pragma unroll
        for (int e = 0; e < 8; ++e) acc[e] += __shfl_xor(acc[e], m, 64);

    if (lane == 0) {
        float l[8]; float mx = -1e30f;
#pragma unroll
        for (int e = 0; e < 8; ++e) { l[e] = acc[e] + br[e]; mx = fmaxf(mx, l[e]); }
        float s = 0.f;
#pragma unroll
        for (int e = 0; e < 8; ++e) { l[e] = __expf(l[e] - mx); s += l[e]; }
        const float inv = 1.0f / s;
#pragma unroll
        for (int e = 0; e < 8; ++e) {
            const float w = l[e] * inv;
            mw[(size_t)n * 8 + e] = (w > 0.05f) ? w : 0.0f;
        }
    }
}

// ---------- Transpose + fp32->bf16 convert (32x32 tiles, per expert z) -------
__global__ __launch_bounds__(256) void moe_tcvt_kernel(
    const float* __restrict__ in, unsigned short* __restrict__ out,
    int ls, size_t in_es, int os, size_t out_es)
{
    __shared__ unsigned short t[32][33];
    const int e = blockIdx.z;
    const int r = threadIdx.x >> 3, c = (threadIdx.x & 7) * 4;
    const float* I = in + (size_t)e * in_es + (size_t)(blockIdx.x * 32 + r) * ls + blockIdx.y * 32 + c;
    f32x4 v = *(const f32x4*)I;
    t[r][c + 0] = f2bf(v[0]); t[r][c + 1] = f2bf(v[1]);
    t[r][c + 2] = f2bf(v[2]); t[r][c + 3] = f2bf(v[3]);
    __syncthreads();
    unsigned short* O = out + (size_t)e * out_es + (size_t)(blockIdx.y * 32 + r) * os + blockIdx.x * 32 + c;
    us4 o;
    o[0] = t[c + 0][r]; o[1] = t[c + 1][r]; o[2] = t[c + 2][r]; o[3] = t[c + 3][r];
    *(us4*)O = o;
}

// ============ 8-phase 256x256 GEMM, BK=64, look-ahead ds_read pipeline =======
// MODE 0: ghid = mw * gelu(hbf @ W1t^T + b1)    (bf16 out, pitch ldc)
// MODE 1: part[z] (+)= ghid[:, klo:klo+kspan] @ W2t^T   (fp32 RMW)
#define MFMA_QUAD(MB, NB, AF, BQ)                                              \
  _Pragma("unroll") for (int mi_ = 0; mi_ < 4; ++mi_)                          \
  _Pragma("unroll") for (int ni_ = 0; ni_ < 2; ++ni_) {                        \
      acc[(MB)+mi_][(NB)+ni_] = __builtin_amdgcn_mfma_f32_16x16x32_bf16(       \
          BQ[ni_][1], AF[mi_][1], __builtin_amdgcn_mfma_f32_16x16x32_bf16(     \
          BQ[ni_][0], AF[mi_][0], acc[(MB)+mi_][(NB)+ni_], 0, 0, 0), 0, 0, 0); \
  }

#define BARX()   __builtin_amdgcn_s_barrier()
#define SBX()    __builtin_amdgcn_sched_barrier(0)
#define LGKM(N)  asm volatile("s_waitcnt lgkmcnt(" #N ")" ::: "memory")
#define VMC(N)   asm volatile("s_waitcnt vmcnt(" #N ")" ::: "memory")
#define PRIO1()  __builtin_amdgcn_s_setprio(1)
#define PRIO0()  __builtin_amdgcn_s_setprio(0)

template <int MODE>
__global__ __launch_bounds__(512) void moe_gemm8p(
    const unsigned short* __restrict__ A, int ldga,
    const unsigned short* __restrict__ Bbase, size_t estride, int ldb,
    const float* __restrict__ b1, const float* __restrict__ mw,
    unsigned short* __restrict__ Cg, int ldc,
    float* __restrict__ part,
    int logFc, int f0glob, int kspan, int init)
{
    __shared__ unsigned short sh[65536];   // 128 KiB: XA,XB,YA,YB (32KB each)
    char* sm = (char*)sh;
    const int XA = 0, XB = 32768, YA = 65536, YB = 98304;

    const int tid = threadIdx.x, lane = tid & 63, wv = tid >> 6;
    const int wr = wv >> 2, wc = wv & 3;

    // XCD-affine bijective block mapping (flat id % 8 == bx-group)
    int bx, by;
    if constexpr (MODE == 0) {
        const int gy = gridDim.y;
        const int orig = blockIdx.x + blockIdx.y * 32;
        const int c8 = orig & 7, j = orig >> 3;       // j in [0, 4*gy)
        bx = c8 * 4 + j / gy; by = j % gy;
    } else {
        const int orig = blockIdx.x + blockIdx.y * 32; // [0,128)
        const int c8 = orig & 7, j = orig >> 3;        // [0,16)
        bx = c8 * 4 + (j >> 2); by = j & 3;
    }
    const int m0 = bx * 256;
    const int n0 = by * 256;

    const int z = (MODE == 1) ? blockIdx.z : 0;
    const int klo = z * kspan;
    float* Cacc = (MODE == 1) ? part + (size_t)z * (8192 * 1024) : nullptr;

    // MODE0 fixed expert / B base
    int e0 = 0, fb = 0;
    const unsigned short* gB0 = nullptr;
    const int rl0 = tid >> 3;                          // row [0,64)
    const int gs8 = ((tid & 7) ^ (rl0 & 7)) * 8;       // XOR-swizzled src col
    if constexpr (MODE == 0) {
        e0 = n0 >> logFc; fb = n0 - (e0 << logFc);
        gB0 = Bbase + (size_t)e0 * estride + (size_t)(fb + rl0) * ldb + gs8;
    }
    const unsigned short* gA0 = A + (size_t)(m0 + rl0) * ldga + gs8;
    const int dstw = wv * 1024;

    auto stageA = [&](int reg, int kk, int q) {
        GLOAD_LDS16(gA0 + kk + (size_t)(q * 64) * ldga,
                    sm + reg + (q >> 1) * 16384 + (q & 1) * 8192 + dstw);
    };
    auto stageB = [&](int reg, int kk, int q) {
        const unsigned short* gb;
        if constexpr (MODE == 0) {
            gb = gB0 + kk;
        } else {
            const int e = kk >> logFc, kc = kk - (e << logFc);
            gb = Bbase + (size_t)e * estride + (size_t)(n0 + rl0) * ldb + kc + gs8;
        }
        GLOAD_LDS16(gb + (size_t)(q * 64) * ldb,
                    sm + reg + (q >> 1) * 16384 + (q & 1) * 8192 + dstw);
    };

    // ds_read swizzled addresses
    const int l15 = lane & 15, l4 = lane >> 4, l7 = lane & 7;
    const int sA0 = (wr * 128 + l15) * 128 + (((0 + l4) ^ l7) << 4);
    const int sA1 = (wr * 128 + l15) * 128 + (((4 + l4) ^ l7) << 4);
    const int sB0 = (wc * 64 + l15) * 128 + (((0 + l4) ^ l7) << 4);
    const int sB1 = (wc * 64 + l15) * 128 + (((4 + l4) ^ l7) << 4);

    f32x4 acc[8][4] = {};
    bf16x8 afL[4][2], afH[4][2], bqL[2][2], bqH[2][2];

#define RD_AFL(BASE) _Pragma("unroll") for (int mi_=0;mi_<4;++mi_){            \
      afL[mi_][0] = *(const bf16x8*)(sm + (BASE) + sA0 + mi_*2048);            \
      afL[mi_][1] = *(const bf16x8*)(sm + (BASE) + sA1 + mi_*2048); }
#define RD_AFH(BASE) _Pragma("unroll") for (int mi_=0;mi_<4;++mi_){            \
      afH[mi_][0] = *(const bf16x8*)(sm + (BASE) + sA0 + (4+mi_)*2048);        \
      afH[mi_][1] = *(const bf16x8*)(sm + (BASE) + sA1 + (4+mi_)*2048); }
#define RD_BQL(BASE) _Pragma("unroll") for (int ni_=0;ni_<2;++ni_){            \
      bqL[ni_][0] = *(const bf16x8*)(sm + (BASE) + sB0 + ni_*2048);            \
      bqL[ni_][1] = *(const bf16x8*)(sm + (BASE) + sB1 + ni_*2048); }
#define RD_BQH(BASE) _Pragma("unroll") for (int ni_=0;ni_<2;++ni_){            \
      bqH[ni_][0] = *(const bf16x8*)(sm + (BASE) + sB0 + (2+ni_)*2048);        \
      bqH[ni_][1] = *(const bf16x8*)(sm + (BASE) + sB1 + (2+ni_)*2048); }

    const int niter = kspan >> 7;  // 2 K-tiles (2x64) per iteration

    // Prologue: stage X(t0), Y(t1); drain X; read X Q1 frags after barrier.
#pragma unroll
    for (int q = 0; q < 4; ++q) { stageA(XA, klo, q); stageB(XB, klo, q); }
#pragma unroll
    for (int q = 0; q < 4; ++q) { stageA(YA, klo + 64, q); stageB(YB, klo + 64, q); }
    VMC(8); SBX();
    BARX();
    RD_AFL(XA); RD_BQL(XB);

    for (int it = 0; it < niter; ++it) {
        const int kX2 = klo + it * 128 + 128;  // next X tile
        const int kY2 = klo + it * 128 + 192;  // next Y tile
        const bool g = (it + 1 < niter);
        // ---- P1: MFMA Q1(X); read-ahead bqH(X)
        RD_BQH(XB);
        BARX(); LGKM(4); SBX(); PRIO1(); MFMA_QUAD(0, 0, afL, bqL); PRIO0(); BARX();
        // ---- P2: MFMA Q2(X); read-ahead afH(X); stage nextX A q0,q2
        RD_AFH(XA);
        if (g) { stageA(XA, kX2, 0); stageA(XA, kX2, 2); }
        BARX(); LGKM(8); SBX(); PRIO1(); MFMA_QUAD(0, 2, afL, bqH); PRIO0(); BARX();
        // ---- P3: MFMA Q3(X); stage nextX B q0,q1
        if (g) { stageB(XB, kX2, 0); stageB(XB, kX2, 1); }
        BARX(); LGKM(0); SBX(); PRIO1(); MFMA_QUAD(4, 0, afH, bqL); PRIO0(); BARX();
        // ---- P4: stage nextX rest; vmcnt; barrier; read Y Q1; MFMA Q4(X)
        if (g) { stageA(XA, kX2, 1); stageA(XA, kX2, 3);
                 stageB(XB, kX2, 2); stageB(XB, kX2, 3);
                 VMC(8); } else { VMC(0); }
        SBX();
        BARX();
        RD_AFL(YA); RD_BQL(YB);
        SBX(); PRIO1(); MFMA_QUAD(4, 2, afH, bqH); PRIO0(); BARX();
        // ---- P5: MFMA Q1(Y); read-ahead bqH(Y)
        RD_BQH(YB);
        BARX(); LGKM(4); SBX(); PRIO1(); MFMA_QUAD(0, 0, afL, bqL); PRIO0(); BARX();
        // ---- P6: MFMA Q2(Y); read-ahead afH(Y); stage nextY A q0,q2
        RD_AFH(YA);
        if (g) { stageA(YA, kY2, 0); stageA(YA, kY2, 2); }
        BARX(); LGKM(8); SBX(); PRIO1(); MFMA_QUAD(0, 2, afL, bqH); PRIO0(); BARX();
        // ---- P7: MFMA Q3(Y); stage nextY B q0,q1
        if (g) { stageB(YB, kY2, 0); stageB(YB, kY2, 1); }
        BARX(); LGKM(0); SBX(); PRIO1(); MFMA_QUAD(4, 0, afH, bqL); PRIO0(); BARX();
        // ---- P8: stage nextY rest; vmcnt; barrier; read nextX Q1; MFMA Q4(Y)
        if (g) { stageA(YA, kY2, 1); stageA(YA, kY2, 3);
                 stageB(YB, kY2, 2); stageB(YB, kY2, 3);
                 VMC(8); } else { VMC(0); }
        SBX();
        BARX();
        if (g) { RD_AFL(XA); RD_BQL(XB); }
        SBX(); PRIO1(); MFMA_QUAD(4, 2, afH, bqH); PRIO0(); BARX();
    }

    // Epilogue
    const int nr0v = l4 * 4;
    if constexpr (MODE == 0) {
        const float* b1p = b1 + (size_t)e0 * 4096 + f0glob + fb;
        f32x4 b1v[4];
#pragma unroll
        for (int j = 0; j < 4; ++j)
            b1v[j] = *(const f32x4*)(b1p + wc * 64 + j * 16 + nr0v);
#pragma unroll
        for (int i = 0; i < 8; ++i) {
            const int token = m0 + wr * 128 + i * 16 + l15;
            const float w = mw[(size_t)token * 8 + e0];
            unsigned short* crow = Cg + (size_t)token * ldc + n0;
#pragma unroll
            for (int j = 0; j < 4; ++j) {
                const int n = wc * 64 + j * 16 + nr0v;
                us4 o;
#pragma unroll
                for (int r = 0; r < 4; ++r)
                    o[r] = f2bf(w * gelu_fast(acc[i][j][r] + b1v[j][r]));
                *(us4*)(crow + n) = o;
            }
        }
    } else {
#pragma unroll
        for (int i = 0; i < 8; ++i) {
            const int row = m0 + wr * 128 + i * 16 + l15;
            float* cp = Cacc + (size_t)row * 1024 + n0;
#pragma unroll
            for (int j = 0; j < 4; ++j) {
                const int n = wc * 64 + j * 16 + nr0v;
                if (init) {
                    *(f32x4*)(cp + n) = acc[i][j];
                } else {
                    f32x4 old = *(const f32x4*)(cp + n);
                    *(f32x4*)(cp + n) = old + acc[i][j];
                }
            }
        }
    }
}

// ------------- Combine: out = sum_z part[z] + sum_e mw*b2 --------------------
__global__ __launch_bounds__(256) void moe_combine_kernel(
    const float* __restrict__ part, int S,
    float* __restrict__ out, const float* __restrict__ mw,
    const float* __restrict__ b2)
{
    const int n = blockIdx.x, t = threadIdx.x;
    const int d = t * 4;
    f32x4 v = *(const f32x4*)(part + (size_t)n * 1024 + d);
    for (int z = 1; z < S; ++z)
        v = v + *(const f32x4*)(part + (size_t)z * (8192 * 1024) + (size_t)n * 1024 + d);
#pragma unroll
    for (int e = 0; e < 8; ++e) {
        const float w = mw[(size_t)n * 8 + e];
        const f32x4 b = *(const f32x4*)(b2 + (size_t)e * 1024 + d);
        v = v + w * b;
    }
    *(f32x4*)(out + (size_t)n * 1024 + d) = v;
}

extern "C" void kernel_launch(void* const* d_in, const int* in_sizes, int n_in,
                              void* d_out, int out_size, void* d_ws, size_t ws_size,
                              hipStream_t stream)
{
    (void)in_sizes; (void)n_in; (void)out_size;
    const float* h  = (const float*)d_in[0];
    const float* Wr = (const float*)d_in[1];
    const float* br = (const float*)d_in[2];
    const float* W1 = (const float*)d_in[3];
    const float* b1 = (const float*)d_in[4];
    const float* W2 = (const float*)d_in[5];
    const float* b2 = (const float*)d_in[6];
    float* out = (float*)d_out;   // fp32 output [N][D]

    const int N = 8192, D = 1024, F = 4096, E = 8;
    const int S = 2;
    auto al = [](size_t x) { return (x + 255) & ~(size_t)255; };
    const size_t sz_hbf = al((size_t)N * D * 2);
    const size_t sz_mw  = al((size_t)N * E * 4);
    const size_t sz_pt1 = al((size_t)N * D * 4);
    // chunk-local weight buffers (no full-transpose path)
    auto tot = [&](int fc) {
        size_t s = sz_hbf + sz_mw + al((size_t)N * ((size_t)E * fc + 32) * 2);
        s += al((size_t)E * fc * D * 2) * 2;
        s += (size_t)S * sz_pt1;
        return s;
    };
    int Fc;
    if      (tot(1024) <= ws_size) Fc = 1024;
    else if (tot(512)  <= ws_size) Fc = 512;
    else                           Fc = 256;
    const int logFc = (Fc == 1024) ? 10 : (Fc == 512) ? 9 : 8;
    const int Kc = E * Fc;
    const int ldAp = Kc + 32;   // padded ghid pitch (breaks pow2 row alias)

    char* p = (char*)d_ws;
    unsigned short* hbf = (unsigned short*)p; p += sz_hbf;
    float* mwp  = (float*)p; p += sz_mw;
    unsigned short* ghid = (unsigned short*)p; p += al((size_t)N * (size_t)ldAp * 2);
    unsigned short* W1t  = (unsigned short*)p; p += al((size_t)E * Fc * D * 2);
    unsigned short* W2t  = (unsigned short*)p; p += al((size_t)E * Fc * D * 2);
    float* part = (float*)p;

    moe_router_kernel<<<N / 4, 256, 0, stream>>>(h, Wr, br, hbf, mwp);

    const int nch = F / Fc;
    for (int c = 0; c < nch; ++c) {
        // chunk-local transposed bf16 weights
        moe_tcvt_kernel<<<dim3(D / 32, Fc / 32, E), 256, 0, stream>>>(
            W1 + (size_t)c * Fc, W1t, F, (size_t)D * F, D, (size_t)Fc * D);
        moe_tcvt_kernel<<<dim3(Fc / 32, D / 32, E), 256, 0, stream>>>(
            W2 + (size_t)c * Fc * D, W2t, D, (size_t)F * D, Fc, (size_t)D * Fc);

        moe_gemm8p<0><<<dim3(32, Kc / 256, 1), 512, 0, stream>>>(
            hbf, 1024, W1t, (size_t)Fc * D, 1024, b1, mwp, ghid, ldAp, nullptr,
            logFc, c * Fc, /*kspan=*/1024, 0);

        moe_gemm8p<1><<<dim3(32, 4, S), 512, 0, stream>>>(
            ghid, ldAp, W2t, (size_t)D * Fc, Fc, nullptr, nullptr, nullptr, 0, part,
            logFc, 0, /*kspan=*/Kc / S, (c == 0) ? 1 : 0);
    }

    moe_combine_kernel<<<N, 256, 0, stream>>>(part, S, out, mwp, b2);
}